// Round 1
// baseline (2489.588 us; speedup 1.0000x reference)
//
#include <hip/hip_runtime.h>

// EncoderALSTM: T=128, B=32, H=256, I=256, 4H=1024.
// Decomposition:
//   k0: pack weights -> ws (W_ihT fp32 transposed; W_hh/W_a transposed, packed f16x8 as uint4)
//   k1: gih[t,b,r] = embs[t,b,:] @ W_ih^T + b_ih + b_hh   (fully parallel, fp32)
//   k2: persistent recurrent kernel, one workgroup per batch element (32 blocks x 1024 thr),
//       whole T-loop with __syncthreads() phase barriers; weights streamed from L2 as f16.
// ws layout (bytes): gih 16777216 | W_ihT 1048576 | W_hhT8 524288 | W_aT8 262144  (~17.8 MB)

#define T_DIM 128
#define B_DIM 32
#define H_DIM 256
#define G_DIM 1024

typedef _Float16 half2_t __attribute__((ext_vector_type(2)));

static __device__ __forceinline__ unsigned pack2(float a, float b) {
  half2_t h;
  h.x = (_Float16)a;
  h.y = (_Float16)b;
  return __builtin_bit_cast(unsigned, h);
}

static __device__ __forceinline__ float dot2f(unsigned w, unsigned v, float acc) {
  half2_t a = __builtin_bit_cast(half2_t, w);
  half2_t b = __builtin_bit_cast(half2_t, v);
#if __has_builtin(__builtin_amdgcn_fdot2)
  return __builtin_amdgcn_fdot2(a, b, acc, false);
#else
  return acc + (float)a.x * (float)b.x + (float)a.y * (float)b.y;
#endif
}

// ---------------- kernel 0: pack/transposed weights ----------------
__global__ void pack_weights(const float* __restrict__ W_ih, const float* __restrict__ W_hh,
                             const float* __restrict__ W_a,
                             float* __restrict__ W_ihT, uint4* __restrict__ W_hhT8,
                             uint4* __restrict__ W_aT8) {
  int n = blockIdx.x * 256 + threadIdx.x;  // 0..262143
  // W_ihT[k][r] = W_ih[r][k], fp32, k<256, r<1024
  {
    int k = n >> 10, r = n & 1023;
    W_ihT[n] = W_ih[r * 256 + k];
  }
  // W_hhT8[k8][r]: uint4 of 8 f16 = W_hh[r][8*k8 .. 8*k8+7], k8<32, r<1024
  if (n < 32768) {
    int k8 = n >> 10, r = n & 1023;
    const float* src = W_hh + r * 256 + k8 * 8;
    uint4 v;
    v.x = pack2(src[0], src[1]);
    v.y = pack2(src[2], src[3]);
    v.z = pack2(src[4], src[5]);
    v.w = pack2(src[6], src[7]);
    W_hhT8[n] = v;
  }
  // W_aT8[k8][j]: uint4 of 8 f16 = W_a[j][8*k8 .. +7], k8<64, j<256
  if (n < 16384) {
    int k8 = n >> 8, j = n & 255;
    const float* src = W_a + j * 512 + k8 * 8;
    uint4 v;
    v.x = pack2(src[0], src[1]);
    v.y = pack2(src[2], src[3]);
    v.z = pack2(src[4], src[5]);
    v.w = pack2(src[6], src[7]);
    W_aT8[n] = v;
  }
}

// ---------------- kernel 1: gih = embs @ W_ih^T + b_ih + b_hh ----------------
__global__ void compute_gih(const float* __restrict__ embs, const float* __restrict__ W_ihT,
                            const float* __restrict__ b_ih, const float* __restrict__ b_hh,
                            float* __restrict__ gih) {
  __shared__ float embS[8][256];
  const int tid = threadIdx.x;        // 256 threads
  const int tb0 = blockIdx.x * 8;     // 512 blocks x 8 (t,b) pairs
#pragma unroll
  for (int e = 0; e < 8; ++e) embS[e][tid] = embs[(size_t)(tb0 + e) * 256 + tid];
  __syncthreads();
  float acc[8][4];
#pragma unroll
  for (int e = 0; e < 8; ++e)
#pragma unroll
    for (int q = 0; q < 4; ++q) acc[e][q] = 0.f;
  for (int k = 0; k < 256; ++k) {
    float w0 = W_ihT[k * 1024 + tid];
    float w1 = W_ihT[k * 1024 + tid + 256];
    float w2 = W_ihT[k * 1024 + tid + 512];
    float w3 = W_ihT[k * 1024 + tid + 768];
#pragma unroll
    for (int e = 0; e < 8; ++e) {
      float x = embS[e][k];
      acc[e][0] += x * w0;
      acc[e][1] += x * w1;
      acc[e][2] += x * w2;
      acc[e][3] += x * w3;
    }
  }
#pragma unroll
  for (int q = 0; q < 4; ++q) {
    float bias = b_ih[q * 256 + tid] + b_hh[q * 256 + tid];
#pragma unroll
    for (int e = 0; e < 8; ++e)
      gih[(size_t)(tb0 + e) * 1024 + q * 256 + tid] = acc[e][q] + bias;
  }
}

// ---------------- kernel 2: persistent recurrent, 1 block per batch elem ----------------
__global__ void __launch_bounds__(1024)
alstm_recurrent(const int* __restrict__ lens, const float* __restrict__ gih,
                const uint4* __restrict__ W_hhT8, const uint4* __restrict__ W_aT8,
                const float* __restrict__ b_a,
                float* __restrict__ out, float* __restrict__ hfin, float* __restrict__ cfin) {
  const int tid = threadIdx.x;
  const int b = blockIdx.x;

  __shared__ float h_s[256];
  __shared__ float c_s[256];
  __shared__ __align__(16) unsigned hp2[128];   // h' packed f16 pairs (256 elems)
  __shared__ __align__(16) unsigned cat2[256];  // [ctx | h] packed f16 pairs (512 elems)
  __shared__ float gates_s[1024];
  __shared__ float sc[128];                     // scores, then alpha
  __shared__ float part[4][256];

  if (tid < 256) { h_s[tid] = 0.f; c_s[tid] = 0.f; }
  if (tid < 128) cat2[128 + tid] = 0u;          // h part of cat = 0
  const int len_b = lens[b];
  __syncthreads();

  for (int t = 0; t < T_DIM; ++t) {
    if (t > 0) {
      // ---- scores[s] = buf[s,b,:] . h  for s < t  (8 lanes per s) ----
      {
        int s = tid >> 3, l8 = tid & 7;
        float a = 0.f;
        if (s < t) {
          const float4* row = (const float4*)out + (size_t)(s * B_DIM + b) * 64;
          const float4* h4 = (const float4*)h_s;
#pragma unroll
          for (int i = 0; i < 8; ++i) {
            float4 v = row[l8 * 8 + i];
            float4 hv = h4[l8 * 8 + i];
            a += v.x * hv.x + v.y * hv.y + v.z * hv.z + v.w * hv.w;
          }
        }
        a += __shfl_xor(a, 1);
        a += __shfl_xor(a, 2);
        a += __shfl_xor(a, 4);
        if (l8 == 0 && s < t) sc[s] = a;
      }
      __syncthreads();
      // ---- softmax over sc[0..t) (first wave) ----
      if (tid < 64) {
        int lane = tid;
        float v0 = (lane < t) ? sc[lane] : -3.0e38f;
        float v1 = (lane + 64 < t) ? sc[lane + 64] : -3.0e38f;
        float m = fmaxf(v0, v1);
#pragma unroll
        for (int off = 32; off >= 1; off >>= 1) m = fmaxf(m, __shfl_xor(m, off));
        float e0 = (lane < t) ? __expf(v0 - m) : 0.f;
        float e1 = (lane + 64 < t) ? __expf(v1 - m) : 0.f;
        float sum = e0 + e1;
#pragma unroll
        for (int off = 32; off >= 1; off >>= 1) sum += __shfl_xor(sum, off);
        float inv = 1.f / sum;
        sc[lane] = e0 * inv;
        sc[lane + 64] = e1 * inv;
      }
      __syncthreads();
      // ---- ctx[j] = sum_s alpha[s]*buf[s,b,j] (4 partials per j) ----
      {
        int j = tid & 255, p = tid >> 8;
        float a = 0.f;
        for (int s = p; s < t; s += 4) a += sc[s] * out[(size_t)(s * B_DIM + b) * 256 + j];
        part[p][j] = a;
      }
      __syncthreads();
      if (tid < 256) {
        float cx = part[0][tid] + part[1][tid] + part[2][tid] + part[3][tid];
        float o = __shfl_xor(cx, 1);
        if (!(tid & 1)) cat2[tid >> 1] = pack2(cx, o);
      }
      __syncthreads();
      // ---- W_a matmul partials: h_att_pre[j] = cat . W_a[j,:] ----
      {
        int j = tid & 255, q = tid >> 8;
        float a = 0.f;
        for (int k8 = q * 16; k8 < q * 16 + 16; ++k8) {
          uint4 w = W_aT8[k8 * 256 + j];
          uint4 cv = *(const uint4*)&cat2[4 * k8];
          a = dot2f(w.x, cv.x, a);
          a = dot2f(w.y, cv.y, a);
          a = dot2f(w.z, cv.z, a);
          a = dot2f(w.w, cv.w, a);
        }
        part[q][j] = a;
      }
      __syncthreads();
    }
    // ---- h' = (t>0) ? tanh(W_a cat + b_a) : h ; pack to hp2 ----
    if (tid < 256) {
      float hpv;
      if (t > 0)
        hpv = tanhf(b_a[tid] + part[0][tid] + part[1][tid] + part[2][tid] + part[3][tid]);
      else
        hpv = h_s[tid];  // == 0 at t=0
      float o = __shfl_xor(hpv, 1);
      if (!(tid & 1)) hp2[tid >> 1] = pack2(hpv, o);
    }
    __syncthreads();
    // ---- gates[r] = gih[t,b,r] + h' . W_hh[r,:] ----
    {
      float acc = gih[(size_t)(t * B_DIM + b) * 1024 + tid];
      for (int k8 = 0; k8 < 32; ++k8) {
        uint4 w = W_hhT8[k8 * 1024 + tid];
        uint4 hv = *(const uint4*)&hp2[4 * k8];
        acc = dot2f(w.x, hv.x, acc);
        acc = dot2f(w.y, hv.y, acc);
        acc = dot2f(w.z, hv.z, acc);
        acc = dot2f(w.w, hv.w, acc);
      }
      gates_s[tid] = acc;
    }
    __syncthreads();
    // ---- pointwise LSTM update, write output ----
    if (tid < 256) {
      float ig = 1.f / (1.f + __expf(-gates_s[tid]));
      float fg = 1.f / (1.f + __expf(-gates_s[tid + 256]));
      float gg = tanhf(gates_s[tid + 512]);
      float og = 1.f / (1.f + __expf(-gates_s[tid + 768]));
      float cn = fg * c_s[tid] + ig * gg;
      float hn = og * tanhf(cn);
      c_s[tid] = cn;
      h_s[tid] = hn;
      out[(size_t)(t * B_DIM + b) * 256 + tid] = hn;
      float o = __shfl_xor(hn, 1);
      if (!(tid & 1)) cat2[128 + (tid >> 1)] = pack2(hn, o);
      if (t == len_b - 1) {
        hfin[b * 256 + tid] = hn;
        cfin[b * 256 + tid] = cn;
      }
    }
    __syncthreads();
  }
}

extern "C" void kernel_launch(void* const* d_in, const int* in_sizes, int n_in,
                              void* d_out, int out_size, void* d_ws, size_t ws_size,
                              hipStream_t stream) {
  const float* embs = (const float*)d_in[0];
  const int* lens = (const int*)d_in[1];
  const float* W_ih = (const float*)d_in[2];
  const float* W_hh = (const float*)d_in[3];
  const float* b_ih = (const float*)d_in[4];
  const float* b_hh = (const float*)d_in[5];
  const float* W_a = (const float*)d_in[6];
  const float* b_a = (const float*)d_in[7];

  float* out = (float*)d_out;                       // [T,B,H]
  float* hfin = out + (size_t)T_DIM * B_DIM * H_DIM; // [B,H]
  float* cfin = hfin + (size_t)B_DIM * H_DIM;        // [B,H]

  char* ws = (char*)d_ws;
  float* gih = (float*)ws;                                   // 16,777,216 B
  float* W_ihT = (float*)(ws + 16777216);                    //  1,048,576 B
  uint4* W_hhT8 = (uint4*)(ws + 16777216 + 1048576);         //    524,288 B
  uint4* W_aT8 = (uint4*)(ws + 16777216 + 1048576 + 524288); //    262,144 B
  // total ws need: ~17.8 MB (assumed <= ws_size)

  pack_weights<<<1024, 256, 0, stream>>>(W_ih, W_hh, W_a, W_ihT, W_hhT8, W_aT8);
  compute_gih<<<512, 256, 0, stream>>>(embs, W_ihT, b_ih, b_hh, gih);
  alstm_recurrent<<<B_DIM, 1024, 0, stream>>>(lens, gih, W_hhT8, W_aT8, b_a, out, hfin, cfin);
}

// Round 2
// 1997.844 us; speedup vs baseline: 1.2461x; 1.2461x over previous
//
#include <hip/hip_runtime.h>

// EncoderALSTM: T=128, B=32, H=256, I=256, 4H=1024.
// Round-2 design: split each batch element across NM=8 blocks (grid=256 = #CUs,
// LDS>80KB forces 1 block/CU -> all co-resident). Block (b,m) owns hidden slice
// [m*32, m*32+32) (=128 gate rows). History kept per-block in LDS (f16 pairs,
// transposed, stride 133 vs bank conflicts); attention computed redundantly.
// 2 device-scope group barriers per step (h' broadcast, h_new broadcast),
// parity-double-buffered data + per-(b,t,phase) one-shot flags.
//
// ws layout (bytes):
//   gih     @ 0         16,777,216  fp32 [t*32+b][1024]
//   W_ihT   @ 16777216   1,048,576  fp32 transposed (for compute_gih)
//   W_hhI   @ 17825792     524,288  uint4 f16x8, [(m*16+i)*256 + tid]
//   W_aI    @ 18350080     262,144  uint4 f16x8, [(m*8+i)*256 + tid]
//   flags   @ 18612224      32,768  int  [b*256 + phase*128 + t]
//   hpbuf   @ 18644992      65,536  fp32 [par][b][256]
//   hnbuf   @ 18710528      65,536  fp32 [par][b][256]

#define T_DIM 128
#define B_DIM 32
#define H_DIM 256

typedef _Float16 half2_t __attribute__((ext_vector_type(2)));

static __device__ __forceinline__ unsigned pack2(float a, float b) {
  half2_t h;
  h.x = (_Float16)a;
  h.y = (_Float16)b;
  return __builtin_bit_cast(unsigned, h);
}

static __device__ __forceinline__ float dot2f(unsigned w, unsigned v, float acc) {
  half2_t a = __builtin_bit_cast(half2_t, w);
  half2_t b = __builtin_bit_cast(half2_t, v);
#if __has_builtin(__builtin_amdgcn_fdot2)
  return __builtin_amdgcn_fdot2(a, b, acc, false);
#else
  return acc + (float)a.x * (float)b.x + (float)a.y * (float)b.y;
#endif
}

// ---------------- kernel 0: pack weights + zero flags ----------------
__global__ void pack_weights(const float* __restrict__ W_ih, const float* __restrict__ W_hh,
                             const float* __restrict__ W_a,
                             float* __restrict__ W_ihT, uint4* __restrict__ W_hhI,
                             uint4* __restrict__ W_aI, int* __restrict__ flags) {
  int n = blockIdx.x * 256 + threadIdx.x;  // 0..262143
  // W_ihT[k][r] = W_ih[r][k], fp32
  {
    int k = n >> 10, r = n & 1023;
    W_ihT[n] = W_ih[r * 256 + k];
  }
  // W_hhI[(m*16+i)*256 + tid] = f16x8 of row r, chunk (half*16+i)
  if (n < 32768) {
    int m = n >> 12, i = (n >> 8) & 15, tidp = n & 255;
    int rl = tidp >> 1, half = tidp & 1;
    int chunk = half * 16 + i;
    int r = (rl >> 5) * 256 + m * 32 + (rl & 31);
    const float* src = W_hh + r * 256 + chunk * 8;
    uint4 v;
    v.x = pack2(src[0], src[1]);
    v.y = pack2(src[2], src[3]);
    v.z = pack2(src[4], src[5]);
    v.w = pack2(src[6], src[7]);
    W_hhI[n] = v;
  }
  // W_aI[(m*8+i)*256 + tid] = f16x8 of row j=m*32+(tid>>3), chunk ((tid&7)*8+i)
  if (n < 16384) {
    int m = n >> 11, i = (n >> 8) & 7, tidp = n & 255;
    int jl = tidp >> 3, part = tidp & 7;
    int chunk = part * 8 + i;
    int j = m * 32 + jl;
    const float* src = W_a + j * 512 + chunk * 8;
    uint4 v;
    v.x = pack2(src[0], src[1]);
    v.y = pack2(src[2], src[3]);
    v.z = pack2(src[4], src[5]);
    v.w = pack2(src[6], src[7]);
    W_aI[n] = v;
  }
  if (n < 8192) flags[n] = 0;
}

// ---------------- kernel 1: gih = embs @ W_ih^T + b_ih + b_hh ----------------
__global__ void compute_gih(const float* __restrict__ embs, const float* __restrict__ W_ihT,
                            const float* __restrict__ b_ih, const float* __restrict__ b_hh,
                            float* __restrict__ gih) {
  __shared__ float embS[8][256];
  const int tid = threadIdx.x;     // 256 threads
  const int tb0 = blockIdx.x * 8;  // 512 blocks x 8 (t,b) pairs
#pragma unroll
  for (int e = 0; e < 8; ++e) embS[e][tid] = embs[(size_t)(tb0 + e) * 256 + tid];
  __syncthreads();
  float acc[8][4];
#pragma unroll
  for (int e = 0; e < 8; ++e)
#pragma unroll
    for (int q = 0; q < 4; ++q) acc[e][q] = 0.f;
  for (int k = 0; k < 256; ++k) {
    float w0 = W_ihT[k * 1024 + tid];
    float w1 = W_ihT[k * 1024 + tid + 256];
    float w2 = W_ihT[k * 1024 + tid + 512];
    float w3 = W_ihT[k * 1024 + tid + 768];
#pragma unroll
    for (int e = 0; e < 8; ++e) {
      float x = embS[e][k];
      acc[e][0] += x * w0;
      acc[e][1] += x * w1;
      acc[e][2] += x * w2;
      acc[e][3] += x * w3;
    }
  }
#pragma unroll
  for (int q = 0; q < 4; ++q) {
    float bias = b_ih[q * 256 + tid] + b_hh[q * 256 + tid];
#pragma unroll
    for (int e = 0; e < 8; ++e)
      gih[(size_t)(tb0 + e) * 1024 + q * 256 + tid] = acc[e][q] + bias;
  }
}

// ---------------- kernel 2: recurrent, 8 blocks per batch elem ----------------
__global__ void alstm_rec(const int* __restrict__ lens, const float* __restrict__ gih,
                          const uint4* __restrict__ W_hhI, const uint4* __restrict__ W_aI,
                          const float* __restrict__ b_a, int* __restrict__ flags,
                          float* __restrict__ hpbuf, float* __restrict__ hnbuf,
                          float* __restrict__ out, float* __restrict__ hfin,
                          float* __restrict__ cfin) {
  extern __shared__ char dynpad[];  // occupancy pad only (forces 1 block/CU)
  const int tid = threadIdx.x;      // 256 threads
  const int b = blockIdx.x & 31;    // members of group b are 32 apart -> same XCD
  const int m = blockIdx.x >> 5;

  __shared__ unsigned histT[17032];  // histT[p*133 + s], f16 pairs, 128x128
  __shared__ unsigned cat2[256];     // [ctx pairs | h pairs]
  __shared__ unsigned hp2[128];      // h' pairs
  __shared__ float sc[128];
  __shared__ float2 cpart[2][128];
  __shared__ float gsl[128];
  __shared__ float c_sl[32];

  const int len_b = lens[b];
  if (len_b == 0x100000) ((volatile char*)dynpad)[tid] = 1;  // keep dyn LDS alive

  if (tid < 128) {
    cat2[128 + tid] = 0u;
    hp2[tid] = 0u;
  }
  if (tid < 32) c_sl[tid] = 0.f;

  const int jl_a = tid >> 3, part_a = tid & 7;
  const float ba_j = b_a[m * 32 + jl_a];

  int* flag1 = flags + b * 256;        // phase 1, index t
  int* flag2 = flags + b * 256 + 128;  // phase 2, index t
  __syncthreads();

  for (int t = 0; t < T_DIM; ++t) {
    const int par = t & 1;
    if (t > 0) {
      // ---- scores[s] = hist[s] . h, f16 dot, 2 lanes per s ----
      {
        const int s = tid >> 1, half = tid & 1;
        float a = 0.f;
        if (s < t) {
          const int p0 = half * 64;
#pragma unroll 8
          for (int i = 0; i < 64; ++i)
            a = dot2f(histT[(p0 + i) * 133 + s], cat2[128 + p0 + i], a);
        }
        a += __shfl_xor(a, 1);
        if (half == 0 && s < t) sc[s] = a;
      }
      __syncthreads();
      // ---- softmax over sc[0..t), first wave ----
      if (tid < 64) {
        float v0 = (tid < t) ? sc[tid] : -3.0e38f;
        float v1 = (tid + 64 < t) ? sc[tid + 64] : -3.0e38f;
        float mx = fmaxf(v0, v1);
#pragma unroll
        for (int off = 32; off >= 1; off >>= 1) mx = fmaxf(mx, __shfl_xor(mx, off));
        float e0 = (tid < t) ? __expf(v0 - mx) : 0.f;
        float e1 = (tid + 64 < t) ? __expf(v1 - mx) : 0.f;
        float sm = e0 + e1;
#pragma unroll
        for (int off = 32; off >= 1; off >>= 1) sm += __shfl_xor(sm, off);
        float inv = 1.f / sm;
        sc[tid] = e0 * inv;
        sc[tid + 64] = e1 * inv;
      }
      __syncthreads();
      // ---- ctx pairs: lane p, 2-way split over s ----
      {
        const int p = tid & 127, ph = tid >> 7;
        float c0 = 0.f, c1 = 0.f;
        for (int s = ph; s < t; s += 2) {
          half2_t hv = __builtin_bit_cast(half2_t, histT[p * 133 + s]);
          float al = sc[s];
          c0 += al * (float)hv.x;
          c1 += al * (float)hv.y;
        }
        cpart[ph][p] = make_float2(c0, c1);
      }
      __syncthreads();
      if (tid < 128) {
        float2 a0 = cpart[0][tid], a1 = cpart[1][tid];
        cat2[tid] = pack2(a0.x + a1.x, a0.y + a1.y);
      }
      __syncthreads();
      // ---- W_a slice: 8 lanes per row j = m*32 + jl_a ----
      {
        float a = 0.f;
        const uint4* wp = W_aI + (size_t)(m * 8) * 256 + tid;
#pragma unroll
        for (int i = 0; i < 8; ++i) {
          uint4 w = wp[i * 256];
          const uint4 cv = *(const uint4*)&cat2[(part_a * 8 + i) * 4];
          a = dot2f(w.x, cv.x, a);
          a = dot2f(w.y, cv.y, a);
          a = dot2f(w.z, cv.z, a);
          a = dot2f(w.w, cv.w, a);
        }
        a += __shfl_xor(a, 1);
        a += __shfl_xor(a, 2);
        a += __shfl_xor(a, 4);
        if (part_a == 0) {
          float hp = tanhf(a + ba_j);
          __hip_atomic_store(&hpbuf[par * 8192 + b * 256 + m * 32 + jl_a], hp,
                             __ATOMIC_RELAXED, __HIP_MEMORY_SCOPE_AGENT);
        }
      }
      __syncthreads();  // drains vmcnt before flag
      if (tid == 0) {
        __hip_atomic_fetch_add(&flag1[t], 1, __ATOMIC_RELEASE, __HIP_MEMORY_SCOPE_AGENT);
        int g = 0;
        while (__hip_atomic_load(&flag1[t], __ATOMIC_ACQUIRE, __HIP_MEMORY_SCOPE_AGENT) < 8 &&
               ++g < (1 << 18))
          __builtin_amdgcn_s_sleep(1);
      }
      __syncthreads();
      if (tid < 128) {
        float x0 = __hip_atomic_load(&hpbuf[par * 8192 + b * 256 + tid * 2],
                                     __ATOMIC_RELAXED, __HIP_MEMORY_SCOPE_AGENT);
        float x1 = __hip_atomic_load(&hpbuf[par * 8192 + b * 256 + tid * 2 + 1],
                                     __ATOMIC_RELAXED, __HIP_MEMORY_SCOPE_AGENT);
        hp2[tid] = pack2(x0, x1);
      }
      __syncthreads();
    }
    // ---- W_hh slice: 2 lanes per gate row; gates -> gsl ----
    {
      const int rl = tid >> 1, half = tid & 1;
      float a = 0.f;
      const uint4* wp = W_hhI + (size_t)(m * 16) * 256 + tid;
#pragma unroll
      for (int i = 0; i < 16; ++i) {
        uint4 w = wp[i * 256];
        const uint4 hv = *(const uint4*)&hp2[(half * 16 + i) * 4];
        a = dot2f(w.x, hv.x, a);
        a = dot2f(w.y, hv.y, a);
        a = dot2f(w.z, hv.z, a);
        a = dot2f(w.w, hv.w, a);
      }
      a += __shfl_xor(a, 1);
      if (half == 0) {
        const int q = rl >> 5, jl = rl & 31;
        gsl[rl] = a + gih[((size_t)t * 32 + b) * 1024 + q * 256 + m * 32 + jl];
      }
    }
    __syncthreads();
    // ---- pointwise LSTM for slice ----
    if (tid < 32) {
      float ig = 1.f / (1.f + __expf(-gsl[tid]));
      float fg = 1.f / (1.f + __expf(-gsl[32 + tid]));
      float gg = tanhf(gsl[64 + tid]);
      float og = 1.f / (1.f + __expf(-gsl[96 + tid]));
      float cn = fg * c_sl[tid] + ig * gg;
      float hn = og * tanhf(cn);
      c_sl[tid] = cn;
      out[((size_t)t * 32 + b) * 256 + m * 32 + tid] = hn;
      __hip_atomic_store(&hnbuf[par * 8192 + b * 256 + m * 32 + tid], hn,
                         __ATOMIC_RELAXED, __HIP_MEMORY_SCOPE_AGENT);
      if (t == len_b - 1) {
        hfin[b * 256 + m * 32 + tid] = hn;
        cfin[b * 256 + m * 32 + tid] = cn;
      }
    }
    __syncthreads();  // drains vmcnt before flag
    if (tid == 0) {
      __hip_atomic_fetch_add(&flag2[t], 1, __ATOMIC_RELEASE, __HIP_MEMORY_SCOPE_AGENT);
      int g = 0;
      while (__hip_atomic_load(&flag2[t], __ATOMIC_ACQUIRE, __HIP_MEMORY_SCOPE_AGENT) < 8 &&
             ++g < (1 << 18))
        __builtin_amdgcn_s_sleep(1);
    }
    __syncthreads();
    // ---- read full h_new: append history + cat2 h-part ----
    if (tid < 128) {
      float x0 = __hip_atomic_load(&hnbuf[par * 8192 + b * 256 + tid * 2],
                                   __ATOMIC_RELAXED, __HIP_MEMORY_SCOPE_AGENT);
      float x1 = __hip_atomic_load(&hnbuf[par * 8192 + b * 256 + tid * 2 + 1],
                                   __ATOMIC_RELAXED, __HIP_MEMORY_SCOPE_AGENT);
      unsigned u = pack2(x0, x1);
      cat2[128 + tid] = u;
      histT[tid * 133 + t] = u;
    }
    __syncthreads();
  }
}

extern "C" void kernel_launch(void* const* d_in, const int* in_sizes, int n_in,
                              void* d_out, int out_size, void* d_ws, size_t ws_size,
                              hipStream_t stream) {
  const float* embs = (const float*)d_in[0];
  const int* lens = (const int*)d_in[1];
  const float* W_ih = (const float*)d_in[2];
  const float* W_hh = (const float*)d_in[3];
  const float* b_ih = (const float*)d_in[4];
  const float* b_hh = (const float*)d_in[5];
  const float* W_a = (const float*)d_in[6];
  const float* b_a = (const float*)d_in[7];

  float* out = (float*)d_out;                        // [T,B,H]
  float* hfin = out + (size_t)T_DIM * B_DIM * H_DIM; // [B,H]
  float* cfin = hfin + (size_t)B_DIM * H_DIM;        // [B,H]

  char* ws = (char*)d_ws;
  float* gih = (float*)ws;
  float* W_ihT = (float*)(ws + 16777216);
  uint4* W_hhI = (uint4*)(ws + 17825792);
  uint4* W_aI = (uint4*)(ws + 18350080);
  int* flags = (int*)(ws + 18612224);
  float* hpbuf = (float*)(ws + 18644992);
  float* hnbuf = (float*)(ws + 18710528);

  pack_weights<<<1024, 256, 0, stream>>>(W_ih, W_hh, W_a, W_ihT, W_hhI, W_aI, flags);
  compute_gih<<<512, 256, 0, stream>>>(embs, W_ihT, b_ih, b_hh, gih);
  alstm_rec<<<256, 256, 16384, stream>>>(lens, gih, W_hhI, W_aI, b_a, flags, hpbuf, hnbuf,
                                         out, hfin, cfin);
}

// Round 3
// 1900.745 us; speedup vs baseline: 1.3098x; 1.0511x over previous
//
#include <hip/hip_runtime.h>

// EncoderALSTM: T=128, B=32, H=256, I=256, 4H=1024.
// Round-3: 8 blocks per batch elem (grid 256 = #CUs, 1 block/CU via 137KB LDS).
// ONE blocking global barrier per step (h_t slice exchange). W_a is pulled off
// the critical path via  Wa_ctx*ctx = sum_s alpha_s * (Wa_ctx*h_s):
// y_s = Wa_ctx*h_s and w_s = Wa_h*h_s are computed split across blocks right
// after the h_s barrier and exchanged DEFERRED (consumed after scores+softmax
// of the next step -> latency hidden). All weights register-resident:
// W_hh slice 64 uints/thread, Wa slices 16+16 uints/thread. History h_s and
// y_s histories in LDS as f16 pairs, XOR-swizzled rows (conflict-free).
//
// ws layout (bytes):
//   gih      @0         16,777,216  fp32 [t*32+b][1024]
//   W_ihT    @16777216   1,048,576  fp32 (for compute_gih)
//   Whh_pack @17825792     524,288  uint4 [m][256][16]
//   Wa_pack  @18350080     262,144  uint4 [m][256][8] (i<4: ctx cols, i>=4: h cols)
//   flags    @18612224      32,768  int [b][256] (0..127: flag1/h, 128..255: flag2/yw)
//   hbuf     @18644992   2,097,152  uint f16-pairs [t*32+b][128]
//   ybuf     @20742144   2,097,152  uint f16-pairs [s*32+b][128]
//   wbuf     @22839296   2,097,152  uint f16-pairs [s*32+b][128]

#define T_DIM 128
#define B_DIM 32

typedef _Float16 half2_t __attribute__((ext_vector_type(2)));

static __device__ __forceinline__ unsigned pack2(float a, float b) {
  half2_t h;
  h.x = (_Float16)a;
  h.y = (_Float16)b;
  return __builtin_bit_cast(unsigned, h);
}

static __device__ __forceinline__ float dot2f(unsigned w, unsigned v, float acc) {
  half2_t a = __builtin_bit_cast(half2_t, w);
  half2_t b = __builtin_bit_cast(half2_t, v);
#if __has_builtin(__builtin_amdgcn_fdot2)
  return __builtin_amdgcn_fdot2(a, b, acc, false);
#else
  return acc + (float)a.x * (float)b.x + (float)a.y * (float)b.y;
#endif
}

static __device__ __forceinline__ float dot8(uint4 w, uint4 v, float acc) {
  acc = dot2f(w.x, v.x, acc);
  acc = dot2f(w.y, v.y, acc);
  acc = dot2f(w.z, v.z, acc);
  acc = dot2f(w.w, v.w, acc);
  return acc;
}

static __device__ __forceinline__ float lo16(unsigned u) {
  return (float)__builtin_bit_cast(half2_t, u).x;
}
static __device__ __forceinline__ float hi16(unsigned u) {
  return (float)__builtin_bit_cast(half2_t, u).y;
}

// ---------------- kernel 0: pack weights + zero flags ----------------
__global__ void pack_weights(const float* __restrict__ W_ih, const float* __restrict__ W_hh,
                             const float* __restrict__ W_a, float* __restrict__ W_ihT,
                             uint4* __restrict__ Whh_pack, uint4* __restrict__ Wa_pack,
                             int* __restrict__ flags) {
  int n = blockIdx.x * 256 + threadIdx.x;  // 0..262143
  {  // W_ihT[k][r] = W_ih[r][k]
    int k = n >> 10, r = n & 1023;
    W_ihT[n] = W_ih[r * 256 + k];
  }
  if (n < 32768) {  // Whh_pack[m][tid][i]
    int m = n >> 12, tid = (n >> 4) & 255, i = n & 15;
    int r_local = tid >> 1, half = tid & 1;
    int q = r_local >> 5, jl = r_local & 31;
    int r = q * 256 + m * 32 + jl;
    int k0 = half * 128 + i * 8;
    const float* src = W_hh + r * 256 + k0;
    uint4 v;
    v.x = pack2(src[0], src[1]);
    v.y = pack2(src[2], src[3]);
    v.z = pack2(src[4], src[5]);
    v.w = pack2(src[6], src[7]);
    Whh_pack[n] = v;
  }
  if (n < 16384) {  // Wa_pack[m][tid][i]
    int m = n >> 11, tid = (n >> 3) & 255, i = n & 7;
    int jl = tid >> 3, part = tid & 7;
    int j = m * 32 + jl;
    int k0 = (i < 4) ? (part * 32 + i * 8) : (256 + part * 32 + (i - 4) * 8);
    const float* src = W_a + j * 512 + k0;
    uint4 v;
    v.x = pack2(src[0], src[1]);
    v.y = pack2(src[2], src[3]);
    v.z = pack2(src[4], src[5]);
    v.w = pack2(src[6], src[7]);
    Wa_pack[n] = v;
  }
  if (n < 8192) flags[n] = 0;
}

// ---------------- kernel 1: gih = embs @ W_ih^T + b_ih + b_hh ----------------
__global__ void compute_gih(const float* __restrict__ embs, const float* __restrict__ W_ihT,
                            const float* __restrict__ b_ih, const float* __restrict__ b_hh,
                            float* __restrict__ gih) {
  __shared__ float embS[8][256];
  const int tid = threadIdx.x;     // 256 threads
  const int tb0 = blockIdx.x * 8;  // 512 blocks x 8 (t,b) pairs
#pragma unroll
  for (int e = 0; e < 8; ++e) embS[e][tid] = embs[(size_t)(tb0 + e) * 256 + tid];
  __syncthreads();
  float acc[8][4];
#pragma unroll
  for (int e = 0; e < 8; ++e)
#pragma unroll
    for (int q = 0; q < 4; ++q) acc[e][q] = 0.f;
  for (int k = 0; k < 256; ++k) {
    float w0 = W_ihT[k * 1024 + tid];
    float w1 = W_ihT[k * 1024 + tid + 256];
    float w2 = W_ihT[k * 1024 + tid + 512];
    float w3 = W_ihT[k * 1024 + tid + 768];
#pragma unroll
    for (int e = 0; e < 8; ++e) {
      float x = embS[e][k];
      acc[e][0] += x * w0;
      acc[e][1] += x * w1;
      acc[e][2] += x * w2;
      acc[e][3] += x * w3;
    }
  }
#pragma unroll
  for (int q = 0; q < 4; ++q) {
    float bias = b_ih[q * 256 + tid] + b_hh[q * 256 + tid];
#pragma unroll
    for (int e = 0; e < 8; ++e)
      gih[(size_t)(tb0 + e) * 1024 + q * 256 + tid] = acc[e][q] + bias;
  }
}

// ---------------- kernel 2: recurrent ----------------
__global__ void __launch_bounds__(256, 1)
alstm_rec(const int* __restrict__ lens, const float* __restrict__ gih,
          const uint4* __restrict__ Whh_pack, const uint4* __restrict__ Wa_pack,
          const float* __restrict__ b_a, int* __restrict__ flags, unsigned* __restrict__ hbuf,
          unsigned* __restrict__ ybuf, unsigned* __restrict__ wbuf, float* __restrict__ out,
          float* __restrict__ hfin, float* __restrict__ cfin) {
  const int tid = threadIdx.x;
  const int b = blockIdx.x & 31;  // group members 32 apart -> same XCD (round-robin %8)
  const int m = blockIdx.x >> 5;

  // LDS: rows of 128 f16-pairs, XOR-swizzled: row r pair p stored at
  //   r*128 + (((p>>2) ^ (r&31))<<2 | (p&3))
  __shared__ __align__(16) unsigned histS[16384];   // h_s history, 64 KB
  __shared__ __align__(16) unsigned ystoreS[16384]; // y_s history, 64 KB
  __shared__ __align__(16) unsigned h2[128];        // h_{t-1} pairs
  __shared__ __align__(16) unsigned hp2[128];       // h' pairs
  __shared__ float sc[128];                         // scores -> alpha
  __shared__ __align__(16) float4 zpart[4][64];
  __shared__ float gsl[128];

  // ---- register-resident weights ----
  uint4 wh4[16];
  {
    const uint4* p = Whh_pack + (size_t)(m * 256 + tid) * 16;
#pragma unroll
    for (int i = 0; i < 16; ++i) wh4[i] = p[i];
  }
  uint4 wy4[4], ww4[4];
  {
    const uint4* p = Wa_pack + (size_t)(m * 256 + tid) * 8;
#pragma unroll
    for (int i = 0; i < 4; ++i) wy4[i] = p[i];
#pragma unroll
    for (int i = 0; i < 4; ++i) ww4[i] = p[4 + i];
  }
  float4 ba4 = make_float4(0.f, 0.f, 0.f, 0.f);
  if (tid < 64) ba4 = *(const float4*)(b_a + 4 * tid);

  const int len_b = lens[b];
  if (tid < 128) hp2[tid] = 0u;
  float c_reg = 0.f;  // cell state, valid lanes tid<32

  int* flag1 = flags + b * 256;        // h exchange, index t
  int* flag2 = flags + b * 256 + 128;  // y/w exchange, index s
  const int r_local = tid >> 1, halfk = tid & 1;
  const int q = r_local >> 5, jl = r_local & 31;
  __syncthreads();

  for (int t = 0; t < T_DIM; ++t) {
    // prefetch gih value for phase F (even lanes use it)
    float gih_v = gih[((size_t)t * 32 + b) * 1024 + q * 256 + m * 32 + jl];

    unsigned w01 = 0, w23 = 0;  // w pairs for phase E (tid<64)
    if (t > 0) {
      // ---- Phase A: y_{t-1}, w_{t-1} slices from h2 (deferred exchange) ----
      {
        const int arow = tid >> 3, apart = tid & 7;
        float ay = 0.f, aw = 0.f;
#pragma unroll
        for (int i = 0; i < 4; ++i) {
          uint4 hc = *(const uint4*)&h2[apart * 16 + i * 4];
          ay = dot8(wy4[i], hc, ay);
          aw = dot8(ww4[i], hc, aw);
        }
        ay += __shfl_xor(ay, 1);
        ay += __shfl_xor(ay, 2);
        ay += __shfl_xor(ay, 4);
        aw += __shfl_xor(aw, 1);
        aw += __shfl_xor(aw, 2);
        aw += __shfl_xor(aw, 4);
        if (apart == 0) {
          float oy = __shfl_xor(ay, 8);
          float ow = __shfl_xor(aw, 8);
          if ((arow & 1) == 0) {
            size_t base = ((size_t)(t - 1) * 32 + b) * 128 + m * 16 + (arow >> 1);
            ybuf[base] = pack2(ay, oy);
            wbuf[base] = pack2(aw, ow);
          }
        }
      }
      // ---- Phase B: scores[s] = hist_s . h_{t-1} (2 lanes/s) ----
      {
        const int s = tid >> 1, sh = tid & 1;
        float a = 0.f;
        if (s < t) {
          const int sx = s & 31;
#pragma unroll 4
          for (int cc = 0; cc < 16; ++cc) {
            const int c = sh * 16 + cc;
            uint4 hv = *(const uint4*)&histS[s * 128 + ((c ^ sx) << 2)];
            uint4 qv = *(const uint4*)&h2[c * 4];
            a = dot8(hv, qv, a);
          }
        }
        a += __shfl_xor(a, 1);
        if (sh == 0 && s < t) sc[s] = a;
      }
      __syncthreads();  // sc visible; phase-A stores drained (vmcnt) for release below
      if (tid == 0)
        __hip_atomic_fetch_add(&flag2[t - 1], 1, __ATOMIC_RELEASE, __HIP_MEMORY_SCOPE_AGENT);
      // ---- Phase C: softmax over sc[0..t) ----
      if (tid < 64) {
        float v0 = (tid < t) ? sc[tid] : -3.0e38f;
        float v1 = (tid + 64 < t) ? sc[tid + 64] : -3.0e38f;
        float mx = fmaxf(v0, v1);
#pragma unroll
        for (int off = 32; off >= 1; off >>= 1) mx = fmaxf(mx, __shfl_xor(mx, off));
        float e0 = (tid < t) ? __expf(v0 - mx) : 0.f;
        float e1 = (tid + 64 < t) ? __expf(v1 - mx) : 0.f;
        float sm = e0 + e1;
#pragma unroll
        for (int off = 32; off >= 1; off >>= 1) sm += __shfl_xor(sm, off);
        float inv = 1.f / sm;
        sc[tid] = e0 * inv;
        sc[tid + 64] = e1 * inv;
      }
      __syncthreads();
      // ---- Phase D: collect y_{t-1}/w_{t-1} (should be ready), z-sum ----
      if (tid == 0) {
        int g = 0;
        while (__hip_atomic_load(&flag2[t - 1], __ATOMIC_ACQUIRE, __HIP_MEMORY_SCOPE_AGENT) < 8 &&
               ++g < (1 << 18)) {}
      }
      __syncthreads();
      if (tid < 128) {
        unsigned yv = ybuf[((size_t)(t - 1) * 32 + b) * 128 + tid];
        ystoreS[(t - 1) * 128 + ((((tid >> 2) ^ ((t - 1) & 31)) << 2) | (tid & 3))] = yv;
      }
      if (tid < 64) {
        uint2 wv = *(const uint2*)(wbuf + ((size_t)(t - 1) * 32 + b) * 128 + 2 * tid);
        w01 = wv.x;
        w23 = wv.y;
      }
      __syncthreads();
      {  // z partial sums: thread (p=tid&63, ph=tid>>6) covers h[4p..4p+3]
        const int p = tid & 63, ph = tid >> 6;
        float4 acc = make_float4(0.f, 0.f, 0.f, 0.f);
        for (int s = ph; s < t; s += 4) {
          float al = sc[s];
          const uint2 yy =
              *(const uint2*)&ystoreS[s * 128 + ((((p >> 1) ^ (s & 31)) << 2) | ((2 * p) & 3))];
          acc.x += al * lo16(yy.x);
          acc.y += al * hi16(yy.x);
          acc.z += al * lo16(yy.y);
          acc.w += al * hi16(yy.y);
        }
        zpart[ph][p] = acc;
      }
      __syncthreads();
      // ---- Phase E: h'[4p..4p+3] = tanh(ba + w + z), pack to hp2 ----
      if (tid < 64) {
        float4 z0 = zpart[0][tid], z1 = zpart[1][tid], z2 = zpart[2][tid], z3 = zpart[3][tid];
        float zx = z0.x + z1.x + z2.x + z3.x;
        float zy = z0.y + z1.y + z2.y + z3.y;
        float zz = z0.z + z1.z + z2.z + z3.z;
        float zw = z0.w + z1.w + z2.w + z3.w;
        float h0 = tanhf(ba4.x + lo16(w01) + zx);
        float h1 = tanhf(ba4.y + hi16(w01) + zy);
        float h2v = tanhf(ba4.z + lo16(w23) + zz);
        float h3 = tanhf(ba4.w + hi16(w23) + zw);
        *(uint2*)&hp2[2 * tid] = make_uint2(pack2(h0, h1), pack2(h2v, h3));
      }
      __syncthreads();
    }
    // ---- Phase F: gates slice: row r_local, k-half halfk ----
    {
      float a = 0.f;
#pragma unroll
      for (int i = 0; i < 16; ++i) {
        uint4 hv = *(const uint4*)&hp2[halfk * 64 + i * 4];
        a = dot8(wh4[i], hv, a);
      }
      a += __shfl_xor(a, 1);
      if (halfk == 0) gsl[r_local] = a + gih_v;
    }
    __syncthreads();
    // ---- Phase G: cell for slice (wave 0, lanes<32) ----
    if (tid < 32) {
      float ig = 1.f / (1.f + __expf(-gsl[tid]));
      float fg = 1.f / (1.f + __expf(-gsl[32 + tid]));
      float gg = tanhf(gsl[64 + tid]);
      float og = 1.f / (1.f + __expf(-gsl[96 + tid]));
      float cn = fg * c_reg + ig * gg;
      float hn = og * tanhf(cn);
      c_reg = cn;
      out[((size_t)t * 32 + b) * 256 + m * 32 + tid] = hn;
      float o = __shfl_xor(hn, 1);
      if (!(tid & 1)) hbuf[((size_t)t * 32 + b) * 128 + m * 16 + (tid >> 1)] = pack2(hn, o);
      if (t == len_b - 1) {
        hfin[b * 256 + m * 32 + tid] = hn;
        cfin[b * 256 + m * 32 + tid] = cn;
      }
    }
    // release + spin by tid0 (same wave as the stores -> program order covers them)
    if (tid == 0) {
      __hip_atomic_fetch_add(&flag1[t], 1, __ATOMIC_RELEASE, __HIP_MEMORY_SCOPE_AGENT);
      int g = 0;
      while (__hip_atomic_load(&flag1[t], __ATOMIC_ACQUIRE, __HIP_MEMORY_SCOPE_AGENT) < 8 &&
             ++g < (1 << 18)) {}
    }
    __syncthreads();
    // ---- Phase H: read full h_t -> h2 + history row t ----
    if (tid < 128) {
      unsigned hv = hbuf[((size_t)t * 32 + b) * 128 + tid];
      h2[tid] = hv;
      histS[t * 128 + ((((tid >> 2) ^ (t & 31)) << 2) | (tid & 3))] = hv;
    }
    __syncthreads();
  }
}

extern "C" void kernel_launch(void* const* d_in, const int* in_sizes, int n_in,
                              void* d_out, int out_size, void* d_ws, size_t ws_size,
                              hipStream_t stream) {
  const float* embs = (const float*)d_in[0];
  const int* lens = (const int*)d_in[1];
  const float* W_ih = (const float*)d_in[2];
  const float* W_hh = (const float*)d_in[3];
  const float* b_ih = (const float*)d_in[4];
  const float* b_hh = (const float*)d_in[5];
  const float* W_a = (const float*)d_in[6];
  const float* b_a = (const float*)d_in[7];

  float* out = (float*)d_out;                         // [T,B,H]
  float* hfin = out + (size_t)T_DIM * B_DIM * 256;    // [B,H]
  float* cfin = hfin + (size_t)B_DIM * 256;           // [B,H]

  char* ws = (char*)d_ws;
  float* gih = (float*)ws;
  float* W_ihT = (float*)(ws + 16777216);
  uint4* Whh_pack = (uint4*)(ws + 17825792);
  uint4* Wa_pack = (uint4*)(ws + 18350080);
  int* flags = (int*)(ws + 18612224);
  unsigned* hbuf = (unsigned*)(ws + 18644992);
  unsigned* ybuf = (unsigned*)(ws + 20742144);
  unsigned* wbuf = (unsigned*)(ws + 22839296);

  pack_weights<<<1024, 256, 0, stream>>>(W_ih, W_hh, W_a, W_ihT, Whh_pack, Wa_pack, flags);
  compute_gih<<<512, 256, 0, stream>>>(embs, W_ihT, b_ih, b_hh, gih);
  alstm_rec<<<256, 256, 0, stream>>>(lens, gih, Whh_pack, Wa_pack, b_a, flags, hbuf, ybuf,
                                     wbuf, out, hfin, cfin);
}

// Round 4
// 698.452 us; speedup vs baseline: 3.5644x; 2.7214x over previous
//
#include <hip/hip_runtime.h>

// EncoderALSTM: T=128, B=32, H=256, I=256, 4H=1024.
// Round-4: 8 blocks per batch elem (grid 256 = #CUs, 512 thr/block).
// ZERO fences. The only cross-block data (h_t slices) moves as tagged u64
// relaxed agent atomics: {pair:f16x2}<<32 | tag(t+1). Relaxed atomics execute
// at the IC coherence point -> no L2 invalidate/writeback storms (Round 2/3's
// 16.5 GB FETCH poison). Attention + h' computed redundantly per block from
// LDS history; full W_a register-resident (32 uint4/thr), W_hh slice 8 uint4.
//
// ws layout (bytes):
//   gih      @0         16,777,216  fp32 [t*32+b][1024]
//   W_ihT    @16777216   1,048,576  fp32 (for compute_gih)
//   Whh_pack @17825792     524,288  uint4 [m][512 thr][8]
//   Wa_pack  @18350080     262,144  uint4 [512 thr][32]
//   hx       @18612224      32,768  u64  [b][128]  tagged h pairs

#define T_DIM 128
#define B_DIM 32

typedef _Float16 half2_t __attribute__((ext_vector_type(2)));

static __device__ __forceinline__ unsigned pack2(float a, float b) {
  half2_t h;
  h.x = (_Float16)a;
  h.y = (_Float16)b;
  return __builtin_bit_cast(unsigned, h);
}

static __device__ __forceinline__ float dot2f(unsigned w, unsigned v, float acc) {
  half2_t a = __builtin_bit_cast(half2_t, w);
  half2_t b = __builtin_bit_cast(half2_t, v);
#if __has_builtin(__builtin_amdgcn_fdot2)
  return __builtin_amdgcn_fdot2(a, b, acc, false);
#else
  return acc + (float)a.x * (float)b.x + (float)a.y * (float)b.y;
#endif
}

static __device__ __forceinline__ float dot8(uint4 w, uint4 v, float acc) {
  acc = dot2f(w.x, v.x, acc);
  acc = dot2f(w.y, v.y, acc);
  acc = dot2f(w.z, v.z, acc);
  acc = dot2f(w.w, v.w, acc);
  return acc;
}

static __device__ __forceinline__ float lo16(unsigned u) {
  return (float)__builtin_bit_cast(half2_t, u).x;
}
static __device__ __forceinline__ float hi16(unsigned u) {
  return (float)__builtin_bit_cast(half2_t, u).y;
}

// ---------------- kernel 0: pack weights + zero hx ----------------
__global__ void pack_weights(const float* __restrict__ W_ih, const float* __restrict__ W_hh,
                             const float* __restrict__ W_a, float* __restrict__ W_ihT,
                             uint4* __restrict__ Whh_pack, uint4* __restrict__ Wa_pack,
                             unsigned* __restrict__ hx32) {
  int n = blockIdx.x * 256 + threadIdx.x;  // 0..262143
  {  // W_ihT[k][r] = W_ih[r][k]
    int k = n >> 10, r = n & 1023;
    W_ihT[n] = W_ih[r * 256 + k];
  }
  if (n < 32768) {  // Whh_pack[m][tid][i]: W_hh[r][cols (4i+qk)*8..+8]
    int m = n >> 12, tid = (n >> 3) & 511, i = n & 7;
    int r_local = tid >> 2, qk = tid & 3;
    int q = r_local >> 5, jl = r_local & 31;
    int r = q * 256 + m * 32 + jl;
    const float* src = W_hh + r * 256 + (4 * i + qk) * 8;
    uint4 v;
    v.x = pack2(src[0], src[1]);
    v.y = pack2(src[2], src[3]);
    v.z = pack2(src[4], src[5]);
    v.w = pack2(src[6], src[7]);
    Whh_pack[n] = v;
  }
  if (n < 16384) {  // Wa_pack[tid][i]: W_a[j][hf*256 + i*8 ..+8], j=tid>>1, hf=tid&1
    int tid = n >> 5, i = n & 31;
    int j = tid >> 1, hf = tid & 1;
    const float* src = W_a + j * 512 + hf * 256 + i * 8;
    uint4 v;
    v.x = pack2(src[0], src[1]);
    v.y = pack2(src[2], src[3]);
    v.z = pack2(src[4], src[5]);
    v.w = pack2(src[6], src[7]);
    Wa_pack[n] = v;
  }
  if (n < 8192) hx32[n] = 0u;  // zero tag buffer (independent of ws poison)
}

// ---------------- kernel 1: gih = embs @ W_ih^T + b_ih + b_hh ----------------
__global__ void compute_gih(const float* __restrict__ embs, const float* __restrict__ W_ihT,
                            const float* __restrict__ b_ih, const float* __restrict__ b_hh,
                            float* __restrict__ gih) {
  __shared__ float embS[8][256];
  const int tid = threadIdx.x;     // 256 threads
  const int tb0 = blockIdx.x * 8;  // 512 blocks x 8 (t,b) pairs
#pragma unroll
  for (int e = 0; e < 8; ++e) embS[e][tid] = embs[(size_t)(tb0 + e) * 256 + tid];
  __syncthreads();
  float acc[8][4];
#pragma unroll
  for (int e = 0; e < 8; ++e)
#pragma unroll
    for (int q = 0; q < 4; ++q) acc[e][q] = 0.f;
  for (int k = 0; k < 256; ++k) {
    float w0 = W_ihT[k * 1024 + tid];
    float w1 = W_ihT[k * 1024 + tid + 256];
    float w2 = W_ihT[k * 1024 + tid + 512];
    float w3 = W_ihT[k * 1024 + tid + 768];
#pragma unroll
    for (int e = 0; e < 8; ++e) {
      float x = embS[e][k];
      acc[e][0] += x * w0;
      acc[e][1] += x * w1;
      acc[e][2] += x * w2;
      acc[e][3] += x * w3;
    }
  }
#pragma unroll
  for (int q = 0; q < 4; ++q) {
    float bias = b_ih[q * 256 + tid] + b_hh[q * 256 + tid];
#pragma unroll
    for (int e = 0; e < 8; ++e)
      gih[(size_t)(tb0 + e) * 1024 + q * 256 + tid] = acc[e][q] + bias;
  }
}

// ---------------- kernel 2: recurrent, 8 blocks/batch, fence-free ----------------
__global__ void __launch_bounds__(512, 2)
alstm_rec(const int* __restrict__ lens, const float* __restrict__ gih,
          const uint4* __restrict__ Whh_pack, const uint4* __restrict__ Wa_pack,
          const float* __restrict__ b_a, unsigned long long* __restrict__ hx,
          float* __restrict__ out, float* __restrict__ hfin, float* __restrict__ cfin) {
  const int tid = threadIdx.x;    // 512 threads
  const int b = blockIdx.x & 31;
  const int m = blockIdx.x >> 5;

  // histS row s, f16 pair p stored at s*128 + (((p>>2)^(s&31))<<2 | (p&3))
  __shared__ __align__(16) unsigned histS[16384];  // 64 KB
  __shared__ __align__(16) unsigned h2[128];       // h_{t-1} pairs
  __shared__ __align__(16) unsigned cat2[256];     // [ctx pairs | h pairs]
  __shared__ __align__(16) unsigned hp2[128];      // h' pairs
  __shared__ float sc[128];
  __shared__ __align__(16) float2 cpart[4][128];
  __shared__ float gsl[128];

  // ---- register-resident weights ----
  uint4 wh4[8];
  {
    const uint4* p = Whh_pack + ((size_t)m * 512 + tid) * 8;
#pragma unroll
    for (int i = 0; i < 8; ++i) wh4[i] = p[i];
  }
  uint4 wa4[32];
  {
    const uint4* p = Wa_pack + (size_t)tid * 32;
#pragma unroll
    for (int i = 0; i < 32; ++i) wa4[i] = p[i];
  }
  const float ba = b_a[tid >> 1];
  const int len_b = lens[b];
  const int r_local = tid >> 2, qk = tid & 3;
  const int gq = r_local >> 5, gjl = r_local & 31;

  if (tid < 128) hp2[tid] = 0u;
  float c_reg = 0.f;  // lanes tid<32
  __syncthreads();

  for (int t = 0; t < T_DIM; ++t) {
    float gih_v = gih[((size_t)t * 32 + b) * 1024 + gq * 256 + m * 32 + gjl];

    if (t > 0) {
      // ---- scores[s] = hist[s] . h_{t-1}, 4 lanes/s, chunks c==part (mod 4) ----
      {
        const int s = tid >> 2, part = tid & 3;
        float a = 0.f;
        if (s < t) {
          const int sx = s & 31;
#pragma unroll
          for (int i = 0; i < 8; ++i) {
            const int c = 4 * i + part;
            uint4 hv = *(const uint4*)&histS[s * 128 + ((c ^ sx) << 2)];
            uint4 qv = *(const uint4*)&h2[c << 2];
            a = dot8(hv, qv, a);
          }
        }
        a += __shfl_xor(a, 1);
        a += __shfl_xor(a, 2);
        if (part == 0 && s < t) sc[s] = a;
      }
      __syncthreads();
      // ---- softmax over sc[0..t) ----
      if (tid < 64) {
        float v0 = (tid < t) ? sc[tid] : -3.0e38f;
        float v1 = (tid + 64 < t) ? sc[tid + 64] : -3.0e38f;
        float mx = fmaxf(v0, v1);
#pragma unroll
        for (int off = 32; off >= 1; off >>= 1) mx = fmaxf(mx, __shfl_xor(mx, off));
        float e0 = (tid < t) ? __expf(v0 - mx) : 0.f;
        float e1 = (tid + 64 < t) ? __expf(v1 - mx) : 0.f;
        float sm = e0 + e1;
#pragma unroll
        for (int off = 32; off >= 1; off >>= 1) sm += __shfl_xor(sm, off);
        float inv = 1.f / sm;
        sc[tid] = e0 * inv;
        sc[tid + 64] = e1 * inv;
      }
      __syncthreads();
      // ---- ctx partials: thread (sp=tid>>7, p2=tid&127) ----
      {
        const int sp = tid >> 7, p2 = tid & 127;
        float c0 = 0.f, c1 = 0.f;
        for (int s = sp; s < t; s += 4) {
          float al = sc[s];
          unsigned hv = histS[s * 128 + ((((p2 >> 2) ^ (s & 31)) << 2) | (p2 & 3))];
          c0 += al * lo16(hv);
          c1 += al * hi16(hv);
        }
        cpart[sp][p2] = make_float2(c0, c1);
      }
      __syncthreads();
      if (tid < 128) {
        float2 a0 = cpart[0][tid], a1 = cpart[1][tid], a2 = cpart[2][tid], a3 = cpart[3][tid];
        cat2[tid] = pack2(a0.x + a1.x + a2.x + a3.x, a0.y + a1.y + a2.y + a3.y);
      }
      __syncthreads();
      // ---- h'[j] = tanh(b_a[j] + Wa[j].cat), j=tid>>1, half hf=tid&1 ----
      {
        const int hf = tid & 1;
        float a = 0.f;
#pragma unroll
        for (int i = 0; i < 32; ++i) {
          uint4 cv = *(const uint4*)&cat2[(hf * 32 + i) * 4];
          a = dot8(wa4[i], cv, a);
        }
        a += __shfl_xor(a, 1);
        if (hf == 0) {
          float v = tanhf(a + ba);
          float o = __shfl_xor(v, 2);
          if (!(tid & 2)) hp2[tid >> 2] = pack2(v, o);
        }
      }
      __syncthreads();
    }
    // ---- gates row r_local: chunks c==qk (mod 4) ----
    {
      float a = 0.f;
#pragma unroll
      for (int i = 0; i < 8; ++i) {
        const int c = 4 * i + qk;
        uint4 hv = *(const uint4*)&hp2[c << 2];
        a = dot8(wh4[i], hv, a);
      }
      a += __shfl_xor(a, 1);
      a += __shfl_xor(a, 2);
      if (qk == 0) gsl[r_local] = a + gih_v;
    }
    __syncthreads();
    // ---- cell for slice (lanes<32) + publish tagged pairs ----
    if (tid < 32) {
      float ig = 1.f / (1.f + __expf(-gsl[tid]));
      float fg = 1.f / (1.f + __expf(-gsl[32 + tid]));
      float gg = tanhf(gsl[64 + tid]);
      float og = 1.f / (1.f + __expf(-gsl[96 + tid]));
      float cn = fg * c_reg + ig * gg;
      float hn = og * tanhf(cn);
      c_reg = cn;
      out[((size_t)t * 32 + b) * 256 + m * 32 + tid] = hn;
      if (t == len_b - 1) {
        hfin[b * 256 + m * 32 + tid] = hn;
        cfin[b * 256 + m * 32 + tid] = cn;
      }
      float o = __shfl_xor(hn, 1);
      if (!(tid & 1)) {
        unsigned long long v =
            ((unsigned long long)pack2(hn, o) << 32) | (unsigned long long)(unsigned)(t + 1);
        __hip_atomic_store(&hx[b * 128 + m * 16 + (tid >> 1)], v, __ATOMIC_RELAXED,
                           __HIP_MEMORY_SCOPE_AGENT);
      }
    }
    // ---- fence-free gather of full h_t (per-word tag poll) ----
    if (tid < 128) {
      const unsigned want = (unsigned)(t + 1);
      unsigned long long v;
      for (;;) {
        v = __hip_atomic_load(&hx[b * 128 + tid], __ATOMIC_RELAXED, __HIP_MEMORY_SCOPE_AGENT);
        if ((unsigned)v == want) break;
        __builtin_amdgcn_s_sleep(1);
      }
      unsigned pair = (unsigned)(v >> 32);
      h2[tid] = pair;
      cat2[128 + tid] = pair;
      histS[t * 128 + ((((tid >> 2) ^ (t & 31)) << 2) | (tid & 3))] = pair;
    }
    __syncthreads();
  }
}

extern "C" void kernel_launch(void* const* d_in, const int* in_sizes, int n_in,
                              void* d_out, int out_size, void* d_ws, size_t ws_size,
                              hipStream_t stream) {
  const float* embs = (const float*)d_in[0];
  const int* lens = (const int*)d_in[1];
  const float* W_ih = (const float*)d_in[2];
  const float* W_hh = (const float*)d_in[3];
  const float* b_ih = (const float*)d_in[4];
  const float* b_hh = (const float*)d_in[5];
  const float* W_a = (const float*)d_in[6];
  const float* b_a = (const float*)d_in[7];

  float* out = (float*)d_out;                       // [T,B,H]
  float* hfin = out + (size_t)T_DIM * B_DIM * 256;  // [B,H]
  float* cfin = hfin + (size_t)B_DIM * 256;         // [B,H]

  char* ws = (char*)d_ws;
  float* gih = (float*)ws;
  float* W_ihT = (float*)(ws + 16777216);
  uint4* Whh_pack = (uint4*)(ws + 17825792);
  uint4* Wa_pack = (uint4*)(ws + 18350080);
  unsigned long long* hx = (unsigned long long*)(ws + 18612224);

  pack_weights<<<1024, 256, 0, stream>>>(W_ih, W_hh, W_a, W_ihT, Whh_pack, Wa_pack,
                                         (unsigned*)hx);
  compute_gih<<<512, 256, 0, stream>>>(embs, W_ihT, b_ih, b_hh, gih);
  alstm_rec<<<256, 512, 0, stream>>>(lens, gih, Whh_pack, Wa_pack, b_a, hx, out, hfin, cfin);
}

// Round 5
// 633.358 us; speedup vs baseline: 3.9308x; 1.1028x over previous
//
#include <hip/hip_runtime.h>

// EncoderALSTM: T=128, B=32, H=256, I=256, 4H=1024.
// Round-5: Round-4 fence-free tagged-atomic transport + Round-3 algebra:
//   Wa_ctx*ctx = sum_s alpha_s * y_s,  y_s = Wa_ctx*h_s,  w_s = Wa_h*h_s.
// Each block computes only its 32-row slice of y/w (no redundant full-W_a
// matvec, no register spill) and publishes {y_j,w_j} as tagged u64 relaxed
// agent atomics right after the h-gather; collection after scores+softmax
// hides the IC round trip. y-history LDS-resident (64 KB, XOR swizzle).
// ZERO fences anywhere.
//
// ws layout (bytes):
//   gih      @0         16,777,216  fp32 [t*32+b][1024]
//   W_ihT    @16777216   1,048,576  fp32 (for compute_gih)
//   Whh_pack @17825792     524,288  uint4 [m][512 thr][8]
//   Wa_pack  @18350080     262,144  uint4 [m][512 thr][4] (0..1 y-cols, 2..3 w-cols)
//   hx       @18612224      32,768  u64 [b][128]  tagged h pairs
//   ywx      @18644992      65,536  u64 [b][256]  tagged {y,w} per row j

#define T_DIM 128
#define B_DIM 32

typedef _Float16 half2_t __attribute__((ext_vector_type(2)));

static __device__ __forceinline__ unsigned pack2(float a, float b) {
  half2_t h;
  h.x = (_Float16)a;
  h.y = (_Float16)b;
  return __builtin_bit_cast(unsigned, h);
}

static __device__ __forceinline__ float dot2f(unsigned w, unsigned v, float acc) {
  half2_t a = __builtin_bit_cast(half2_t, w);
  half2_t b = __builtin_bit_cast(half2_t, v);
#if __has_builtin(__builtin_amdgcn_fdot2)
  return __builtin_amdgcn_fdot2(a, b, acc, false);
#else
  return acc + (float)a.x * (float)b.x + (float)a.y * (float)b.y;
#endif
}

static __device__ __forceinline__ float dot8(uint4 w, uint4 v, float acc) {
  acc = dot2f(w.x, v.x, acc);
  acc = dot2f(w.y, v.y, acc);
  acc = dot2f(w.z, v.z, acc);
  acc = dot2f(w.w, v.w, acc);
  return acc;
}

static __device__ __forceinline__ float lo16(unsigned u) {
  return (float)__builtin_bit_cast(half2_t, u).x;
}
static __device__ __forceinline__ float hi16(unsigned u) {
  return (float)__builtin_bit_cast(half2_t, u).y;
}

// ---------------- kernel 0: pack weights + zero hx/ywx ----------------
__global__ void pack_weights(const float* __restrict__ W_ih, const float* __restrict__ W_hh,
                             const float* __restrict__ W_a, float* __restrict__ W_ihT,
                             uint4* __restrict__ Whh_pack, uint4* __restrict__ Wa_pack,
                             unsigned* __restrict__ zbuf) {
  int n = blockIdx.x * 256 + threadIdx.x;  // 0..262143
  {  // W_ihT[k][r] = W_ih[r][k]
    int k = n >> 10, r = n & 1023;
    W_ihT[n] = W_ih[r * 256 + k];
  }
  if (n < 32768) {  // Whh_pack[m][tid][i]: W_hh[r][(4i+qk)*8 ..+8]
    int m = n >> 12, tid = (n >> 3) & 511, i = n & 7;
    int r_local = tid >> 2, qk = tid & 3;
    int q = r_local >> 5, jl = r_local & 31;
    int r = q * 256 + m * 32 + jl;
    const float* src = W_hh + r * 256 + (4 * i + qk) * 8;
    uint4 v;
    v.x = pack2(src[0], src[1]);
    v.y = pack2(src[2], src[3]);
    v.z = pack2(src[4], src[5]);
    v.w = pack2(src[6], src[7]);
    Whh_pack[n] = v;
  }
  if (n < 16384) {  // Wa_pack[m][tid][i]: j=m*32+(tid>>4), part=tid&15
    int m = n >> 11, tid = (n >> 2) & 511, i = n & 3;
    int j = m * 32 + (tid >> 4), part = tid & 15;
    int col0 = (i < 2) ? (part * 16 + i * 8) : (256 + part * 16 + (i - 2) * 8);
    const float* src = W_a + j * 512 + col0;
    uint4 v;
    v.x = pack2(src[0], src[1]);
    v.y = pack2(src[2], src[3]);
    v.z = pack2(src[4], src[5]);
    v.w = pack2(src[6], src[7]);
    Wa_pack[n] = v;
  }
  if (n < 24576) zbuf[n] = 0u;  // zero hx (8192 u32) + ywx (16384 u32)
}

// ---------------- kernel 1: gih = embs @ W_ih^T + b_ih + b_hh ----------------
__global__ void compute_gih(const float* __restrict__ embs, const float* __restrict__ W_ihT,
                            const float* __restrict__ b_ih, const float* __restrict__ b_hh,
                            float* __restrict__ gih) {
  __shared__ float embS[8][256];
  const int tid = threadIdx.x;     // 256 threads
  const int tb0 = blockIdx.x * 8;  // 512 blocks x 8 (t,b) pairs
#pragma unroll
  for (int e = 0; e < 8; ++e) embS[e][tid] = embs[(size_t)(tb0 + e) * 256 + tid];
  __syncthreads();
  float acc[8][4];
#pragma unroll
  for (int e = 0; e < 8; ++e)
#pragma unroll
    for (int q = 0; q < 4; ++q) acc[e][q] = 0.f;
  for (int k = 0; k < 256; ++k) {
    float w0 = W_ihT[k * 1024 + tid];
    float w1 = W_ihT[k * 1024 + tid + 256];
    float w2 = W_ihT[k * 1024 + tid + 512];
    float w3 = W_ihT[k * 1024 + tid + 768];
#pragma unroll
    for (int e = 0; e < 8; ++e) {
      float x = embS[e][k];
      acc[e][0] += x * w0;
      acc[e][1] += x * w1;
      acc[e][2] += x * w2;
      acc[e][3] += x * w3;
    }
  }
#pragma unroll
  for (int q = 0; q < 4; ++q) {
    float bias = b_ih[q * 256 + tid] + b_hh[q * 256 + tid];
#pragma unroll
    for (int e = 0; e < 8; ++e)
      gih[(size_t)(tb0 + e) * 1024 + q * 256 + tid] = acc[e][q] + bias;
  }
}

// ---------------- kernel 2: recurrent, fence-free, y/w split ----------------
__global__ void __launch_bounds__(512, 1)
alstm_rec(const int* __restrict__ lens, const float* __restrict__ gih,
          const uint4* __restrict__ Whh_pack, const uint4* __restrict__ Wa_pack,
          const float* __restrict__ b_a, unsigned long long* __restrict__ hx,
          unsigned long long* __restrict__ ywx, float* __restrict__ out,
          float* __restrict__ hfin, float* __restrict__ cfin) {
  const int tid = threadIdx.x;  // 512 threads
  const int b = blockIdx.x & 31;
  const int m = blockIdx.x >> 5;

  // row s, f16 pair p stored at s*128 + (((p>>2)^(s&31))<<2 | (p&3))
  __shared__ __align__(16) unsigned histS[16384];   // h history, 64 KB
  __shared__ __align__(16) unsigned ystoreS[16384]; // y history, 64 KB
  __shared__ __align__(16) unsigned h2[128];        // h_{t-1} pairs
  __shared__ __align__(16) unsigned hp2[128];       // h' pairs
  __shared__ float sc[128];
  __shared__ float zpartF[4][256];
  __shared__ float gsl[128];

  // ---- register-resident weights ----
  uint4 wh4[8];
  {
    const uint4* p = Whh_pack + ((size_t)m * 512 + tid) * 8;
#pragma unroll
    for (int i = 0; i < 8; ++i) wh4[i] = p[i];
  }
  uint4 wa4[4];  // [0..1] y-cols, [2..3] w-cols for row j=m*32+(tid>>4), part=tid&15
  {
    const uint4* p = Wa_pack + ((size_t)m * 512 + tid) * 4;
#pragma unroll
    for (int i = 0; i < 4; ++i) wa4[i] = p[i];
  }
  const float ba_j = (tid < 256) ? b_a[tid] : 0.f;
  const int len_b = lens[b];
  const int r_local = tid >> 2, qk = tid & 3;
  const int gq = r_local >> 5, gjl = r_local & 31;
  const int part_a = tid & 15;

  if (tid < 128) hp2[tid] = 0u;
  float c_reg = 0.f;  // lanes tid<32
  __syncthreads();

  for (int t = 0; t < T_DIM; ++t) {
    float gih_v = gih[((size_t)t * 32 + b) * 1024 + gq * 256 + m * 32 + gjl];

    float w_j = 0.f;  // Wa_h*h_{t-1} for row tid (valid tid<256 after collect)
    if (t > 0) {
      // ---- Phase Y: publish y/w slice of h_{t-1} (deferred consumption) ----
      {
        uint4 hc0 = *(const uint4*)&h2[part_a * 8];
        uint4 hc1 = *(const uint4*)&h2[part_a * 8 + 4];
        float ay = dot8(wa4[0], hc0, 0.f);
        ay = dot8(wa4[1], hc1, ay);
        float aw = dot8(wa4[2], hc0, 0.f);
        aw = dot8(wa4[3], hc1, aw);
        ay += __shfl_xor(ay, 1);
        ay += __shfl_xor(ay, 2);
        ay += __shfl_xor(ay, 4);
        ay += __shfl_xor(ay, 8);
        aw += __shfl_xor(aw, 1);
        aw += __shfl_xor(aw, 2);
        aw += __shfl_xor(aw, 4);
        aw += __shfl_xor(aw, 8);
        if (part_a == 0) {
          unsigned long long v =
              ((unsigned long long)pack2(ay, aw) << 32) | (unsigned long long)(unsigned)t;
          __hip_atomic_store(&ywx[b * 256 + m * 32 + (tid >> 4)], v, __ATOMIC_RELAXED,
                             __HIP_MEMORY_SCOPE_AGENT);
        }
      }
      // ---- Phase S: scores[s] = hist[s] . h_{t-1}, 4 lanes/s ----
      {
        const int s = tid >> 2, part = tid & 3;
        float a = 0.f;
        if (s < t) {
          const int sx = s & 31;
#pragma unroll
          for (int i = 0; i < 8; ++i) {
            const int c = 4 * i + part;
            uint4 hv = *(const uint4*)&histS[s * 128 + ((c ^ sx) << 2)];
            uint4 qv = *(const uint4*)&h2[c << 2];
            a = dot8(hv, qv, a);
          }
        }
        a += __shfl_xor(a, 1);
        a += __shfl_xor(a, 2);
        if (part == 0 && s < t) sc[s] = a;
      }
      __syncthreads();
      // ---- softmax over sc[0..t) ----
      if (tid < 64) {
        float v0 = (tid < t) ? sc[tid] : -3.0e38f;
        float v1 = (tid + 64 < t) ? sc[tid + 64] : -3.0e38f;
        float mx = fmaxf(v0, v1);
#pragma unroll
        for (int off = 32; off >= 1; off >>= 1) mx = fmaxf(mx, __shfl_xor(mx, off));
        float e0 = (tid < t) ? __expf(v0 - mx) : 0.f;
        float e1 = (tid + 64 < t) ? __expf(v1 - mx) : 0.f;
        float sm = e0 + e1;
#pragma unroll
        for (int off = 32; off >= 1; off >>= 1) sm += __shfl_xor(sm, off);
        float inv = 1.f / sm;
        sc[tid] = e0 * inv;
        sc[tid + 64] = e1 * inv;
      }
      __syncthreads();
      // ---- Phase C: collect y/w of t-1 (tag poll), store y row t-1 ----
      if (tid < 256) {
        unsigned long long v;
        for (;;) {
          v = __hip_atomic_load(&ywx[b * 256 + tid], __ATOMIC_RELAXED, __HIP_MEMORY_SCOPE_AGENT);
          if ((unsigned)v == (unsigned)t) break;
          __builtin_amdgcn_s_sleep(1);
        }
        unsigned py = (unsigned)(v >> 32);  // lo16=y_j, hi16=w_j
        w_j = hi16(py);
        unsigned ny = (unsigned)__shfl_xor((int)py, 1);
        if (!(tid & 1)) {
          unsigned pair = (py & 0xFFFFu) | (ny << 16);
          const int p = tid >> 1, sx = (t - 1) & 31;
          ystoreS[(t - 1) * 128 + ((((p >> 2) ^ sx) << 2) | (p & 3))] = pair;
        }
      }
      __syncthreads();
      // ---- Phase Z: z partials over y history ----
      {
        const int sp = tid >> 7, p2 = tid & 127;
        float c0 = 0.f, c1 = 0.f;
        for (int s = sp; s < t; s += 4) {
          float al = sc[s];
          unsigned yv = ystoreS[s * 128 + ((((p2 >> 2) ^ (s & 31)) << 2) | (p2 & 3))];
          c0 += al * lo16(yv);
          c1 += al * hi16(yv);
        }
        zpartF[sp][2 * p2] = c0;
        zpartF[sp][2 * p2 + 1] = c1;
      }
      __syncthreads();
      // ---- Phase H': h'_j = tanh(ba + w + z), pack pairs ----
      if (tid < 256) {
        float z = zpartF[0][tid] + zpartF[1][tid] + zpartF[2][tid] + zpartF[3][tid];
        float hv = tanhf(ba_j + w_j + z);
        float o = __shfl_xor(hv, 1);
        if (!(tid & 1)) hp2[tid >> 1] = pack2(hv, o);
      }
      __syncthreads();
    }
    // ---- gates row r_local: chunks c==qk (mod 4) ----
    {
      float a = 0.f;
#pragma unroll
      for (int i = 0; i < 8; ++i) {
        const int c = 4 * i + qk;
        uint4 hv = *(const uint4*)&hp2[c << 2];
        a = dot8(wh4[i], hv, a);
      }
      a += __shfl_xor(a, 1);
      a += __shfl_xor(a, 2);
      if (qk == 0) gsl[r_local] = a + gih_v;
    }
    __syncthreads();
    // ---- cell for slice (lanes<32) + publish tagged h pairs ----
    if (tid < 32) {
      float ig = 1.f / (1.f + __expf(-gsl[tid]));
      float fg = 1.f / (1.f + __expf(-gsl[32 + tid]));
      float gg = tanhf(gsl[64 + tid]);
      float og = 1.f / (1.f + __expf(-gsl[96 + tid]));
      float cn = fg * c_reg + ig * gg;
      float hn = og * tanhf(cn);
      c_reg = cn;
      out[((size_t)t * 32 + b) * 256 + m * 32 + tid] = hn;
      if (t == len_b - 1) {
        hfin[b * 256 + m * 32 + tid] = hn;
        cfin[b * 256 + m * 32 + tid] = cn;
      }
      float o = __shfl_xor(hn, 1);
      if (!(tid & 1)) {
        unsigned long long v =
            ((unsigned long long)pack2(hn, o) << 32) | (unsigned long long)(unsigned)(t + 1);
        __hip_atomic_store(&hx[b * 128 + m * 16 + (tid >> 1)], v, __ATOMIC_RELAXED,
                           __HIP_MEMORY_SCOPE_AGENT);
      }
    }
    // ---- fence-free gather of full h_t ----
    if (tid < 128) {
      const unsigned want = (unsigned)(t + 1);
      unsigned long long v;
      for (;;) {
        v = __hip_atomic_load(&hx[b * 128 + tid], __ATOMIC_RELAXED, __HIP_MEMORY_SCOPE_AGENT);
        if ((unsigned)v == want) break;
        __builtin_amdgcn_s_sleep(1);
      }
      unsigned pair = (unsigned)(v >> 32);
      h2[tid] = pair;
      histS[t * 128 + ((((tid >> 2) ^ (t & 31)) << 2) | (tid & 3))] = pair;
    }
    __syncthreads();
  }
}

extern "C" void kernel_launch(void* const* d_in, const int* in_sizes, int n_in,
                              void* d_out, int out_size, void* d_ws, size_t ws_size,
                              hipStream_t stream) {
  const float* embs = (const float*)d_in[0];
  const int* lens = (const int*)d_in[1];
  const float* W_ih = (const float*)d_in[2];
  const float* W_hh = (const float*)d_in[3];
  const float* b_ih = (const float*)d_in[4];
  const float* b_hh = (const float*)d_in[5];
  const float* W_a = (const float*)d_in[6];
  const float* b_a = (const float*)d_in[7];

  float* out = (float*)d_out;                       // [T,B,H]
  float* hfin = out + (size_t)T_DIM * B_DIM * 256;  // [B,H]
  float* cfin = hfin + (size_t)B_DIM * 256;         // [B,H]

  char* ws = (char*)d_ws;
  float* gih = (float*)ws;
  float* W_ihT = (float*)(ws + 16777216);
  uint4* Whh_pack = (uint4*)(ws + 17825792);
  uint4* Wa_pack = (uint4*)(ws + 18350080);
  unsigned long long* hx = (unsigned long long*)(ws + 18612224);
  unsigned long long* ywx = (unsigned long long*)(ws + 18644992);

  pack_weights<<<1024, 256, 0, stream>>>(W_ih, W_hh, W_a, W_ihT, Whh_pack, Wa_pack,
                                         (unsigned*)hx);
  compute_gih<<<512, 256, 0, stream>>>(embs, W_ihT, b_ih, b_hh, gih);
  alstm_rec<<<256, 512, 0, stream>>>(lens, gih, Whh_pack, Wa_pack, b_a, hx, ywx, out, hfin,
                                     cfin);
}

// Round 6
// 623.323 us; speedup vs baseline: 3.9941x; 1.0161x over previous
//
#include <hip/hip_runtime.h>

// EncoderALSTM: T=128, B=32, H=256, I=256, 4H=1024.
// Round-6: ONE poll point per step. Blocks publish, at step end:
//   (a) their h_t slice (16 tagged u64 pairs), and
//   (b) y/w PARTIALS for all 256 j from their own slice:
//       y_part^m[j] = Wa_ctx[j, m*32..+32) . h_slice, w_part^m[j] likewise,
//       packed {y,w} f16x2 + tag as u64 at ywp[b][m][j].
// Consumer (next step top) polls both concurrently with disjoint thread
// groups (tid<256: partials, 8 coalesced loads each; tid 256..383: h pairs),
// reduces 8 partials per j -> y_{t-1}[j] (LDS history) and w_j (register).
// Fast tanh/sigmoid via v_exp+v_rcp on the critical chain. ZERO fences.
//
// ws layout (bytes):
//   gih      @0         16,777,216  fp32 [t*32+b][1024]
//   W_ihT    @16777216   1,048,576  fp32 (for compute_gih)
//   Whh_pack @17825792     524,288  uint4 [m][512 thr][8]
//   Wa_pack  @18350080     262,144  uint4 [m][512 thr][4] (thr=(j,type), 32 slice cols)
//   ywp      @18612224     524,288  u64 [32 b][8 m][256 j] tagged {y,w} partials
//   hx       @19136512      32,768  u64 [32 b][128] tagged h pairs

#define T_DIM 128
#define B_DIM 32

typedef _Float16 half2_t __attribute__((ext_vector_type(2)));

static __device__ __forceinline__ unsigned pack2(float a, float b) {
  half2_t h;
  h.x = (_Float16)a;
  h.y = (_Float16)b;
  return __builtin_bit_cast(unsigned, h);
}

static __device__ __forceinline__ float dot2f(unsigned w, unsigned v, float acc) {
  half2_t a = __builtin_bit_cast(half2_t, w);
  half2_t b = __builtin_bit_cast(half2_t, v);
#if __has_builtin(__builtin_amdgcn_fdot2)
  return __builtin_amdgcn_fdot2(a, b, acc, false);
#else
  return acc + (float)a.x * (float)b.x + (float)a.y * (float)b.y;
#endif
}

static __device__ __forceinline__ float dot8(uint4 w, uint4 v, float acc) {
  acc = dot2f(w.x, v.x, acc);
  acc = dot2f(w.y, v.y, acc);
  acc = dot2f(w.z, v.z, acc);
  acc = dot2f(w.w, v.w, acc);
  return acc;
}

static __device__ __forceinline__ float lo16(unsigned u) {
  return (float)__builtin_bit_cast(half2_t, u).x;
}
static __device__ __forceinline__ float hi16(unsigned u) {
  return (float)__builtin_bit_cast(half2_t, u).y;
}

// fast sigmoid/tanh: v_exp_f32 + v_rcp_f32 (f16-level accuracy is plenty)
static __device__ __forceinline__ float fsig(float x) {
  return __builtin_amdgcn_rcpf(1.f + __expf(-x));
}
static __device__ __forceinline__ float ftanh(float x) {
  float e = __expf(2.f * x);
  return 1.f - 2.f * __builtin_amdgcn_rcpf(e + 1.f);
}

// ---------------- kernel 0: pack weights + zero tag buffers ----------------
__global__ void pack_weights(const float* __restrict__ W_ih, const float* __restrict__ W_hh,
                             const float* __restrict__ W_a, float* __restrict__ W_ihT,
                             uint4* __restrict__ Whh_pack, uint4* __restrict__ Wa_pack,
                             unsigned long long* __restrict__ ywp,
                             unsigned long long* __restrict__ hx) {
  int n = blockIdx.x * 256 + threadIdx.x;  // 0..262143
  {  // W_ihT[k][r] = W_ih[r][k]
    int k = n >> 10, r = n & 1023;
    W_ihT[n] = W_ih[r * 256 + k];
  }
  if (n < 32768) {  // Whh_pack[m][tid][i]: W_hh[r][(4i+qk)*8 ..+8]
    int m = n >> 12, tid = (n >> 3) & 511, i = n & 7;
    int r_local = tid >> 2, qk = tid & 3;
    int q = r_local >> 5, jl = r_local & 31;
    int r = q * 256 + m * 32 + jl;
    const float* src = W_hh + r * 256 + (4 * i + qk) * 8;
    uint4 v;
    v.x = pack2(src[0], src[1]);
    v.y = pack2(src[2], src[3]);
    v.z = pack2(src[4], src[5]);
    v.w = pack2(src[6], src[7]);
    Whh_pack[n] = v;
  }
  if (n < 16384) {  // Wa_pack[m][thr][c]: thr=(j=thr>>1, type=thr&1), cols m*32+c*8..+8
    int m = n >> 11, thr = (n >> 2) & 511, c = n & 3;
    int j = thr >> 1, type = thr & 1;
    int col0 = type * 256 + m * 32 + c * 8;
    const float* src = W_a + j * 512 + col0;
    uint4 v;
    v.x = pack2(src[0], src[1]);
    v.y = pack2(src[2], src[3]);
    v.z = pack2(src[4], src[5]);
    v.w = pack2(src[6], src[7]);
    Wa_pack[n] = v;
  }
  // zero tag buffers via the same atomic path used by the recurrent kernel
  if (n < 65536)
    __hip_atomic_store(&ywp[n], 0ull, __ATOMIC_RELAXED, __HIP_MEMORY_SCOPE_AGENT);
  else if (n < 69632)
    __hip_atomic_store(&hx[n - 65536], 0ull, __ATOMIC_RELAXED, __HIP_MEMORY_SCOPE_AGENT);
}

// ---------------- kernel 1: gih = embs @ W_ih^T + b_ih + b_hh ----------------
__global__ void compute_gih(const float* __restrict__ embs, const float* __restrict__ W_ihT,
                            const float* __restrict__ b_ih, const float* __restrict__ b_hh,
                            float* __restrict__ gih) {
  __shared__ float embS[8][256];
  const int tid = threadIdx.x;     // 256 threads
  const int tb0 = blockIdx.x * 8;  // 512 blocks x 8 (t,b) pairs
#pragma unroll
  for (int e = 0; e < 8; ++e) embS[e][tid] = embs[(size_t)(tb0 + e) * 256 + tid];
  __syncthreads();
  float acc[8][4];
#pragma unroll
  for (int e = 0; e < 8; ++e)
#pragma unroll
    for (int q = 0; q < 4; ++q) acc[e][q] = 0.f;
  for (int k = 0; k < 256; ++k) {
    float w0 = W_ihT[k * 1024 + tid];
    float w1 = W_ihT[k * 1024 + tid + 256];
    float w2 = W_ihT[k * 1024 + tid + 512];
    float w3 = W_ihT[k * 1024 + tid + 768];
#pragma unroll
    for (int e = 0; e < 8; ++e) {
      float x = embS[e][k];
      acc[e][0] += x * w0;
      acc[e][1] += x * w1;
      acc[e][2] += x * w2;
      acc[e][3] += x * w3;
    }
  }
#pragma unroll
  for (int q = 0; q < 4; ++q) {
    float bias = b_ih[q * 256 + tid] + b_hh[q * 256 + tid];
#pragma unroll
    for (int e = 0; e < 8; ++e)
      gih[(size_t)(tb0 + e) * 1024 + q * 256 + tid] = acc[e][q] + bias;
  }
}

// ---------------- kernel 2: recurrent, one poll point per step ----------------
__global__ void __launch_bounds__(512, 1)
alstm_rec(const int* __restrict__ lens, const float* __restrict__ gih,
          const uint4* __restrict__ Whh_pack, const uint4* __restrict__ Wa_pack,
          const float* __restrict__ b_a, unsigned long long* __restrict__ hx,
          unsigned long long* __restrict__ ywp, float* __restrict__ out,
          float* __restrict__ hfin, float* __restrict__ cfin) {
  const int tid = threadIdx.x;  // 512 threads
  const int b = blockIdx.x & 31;
  const int m = blockIdx.x >> 5;

  // row s, f16 pair p stored at s*128 + (((p>>2)^(s&31))<<2 | (p&3))
  __shared__ __align__(16) unsigned histS[16384];    // h history, 64 KB
  __shared__ __align__(16) unsigned ystoreS[16384];  // y history, 64 KB
  __shared__ __align__(16) unsigned h2[128];         // h_{t-1} pairs
  __shared__ __align__(16) unsigned hp2[128];        // h' pairs
  __shared__ __align__(16) unsigned hsl2[16];        // own h_t slice pairs
  __shared__ float sc[128];
  __shared__ float zpartF[4][256];
  __shared__ float gsl[128];

  // ---- register-resident weights ----
  uint4 wh4[8];
  {
    const uint4* p = Whh_pack + ((size_t)m * 512 + tid) * 8;
#pragma unroll
    for (int i = 0; i < 8; ++i) wh4[i] = p[i];
  }
  uint4 wa4[4];  // slice cols for (j=tid>>1, type=tid&1)
  {
    const uint4* p = Wa_pack + ((size_t)m * 512 + tid) * 4;
#pragma unroll
    for (int i = 0; i < 4; ++i) wa4[i] = p[i];
  }
  const float ba_j = (tid < 256) ? b_a[tid] : 0.f;
  const int len_b = lens[b];
  const int r_local = tid >> 2, qk = tid & 3;
  const int gq = r_local >> 5, gjl = r_local & 31;

  if (tid < 128) hp2[tid] = 0u;
  float c_reg = 0.f;  // lanes tid<32
  __syncthreads();

  for (int t = 0; t < T_DIM; ++t) {
    float gih_v = gih[((size_t)t * 32 + b) * 1024 + gq * 256 + m * 32 + gjl];
    float w_j = 0.f;

    if (t > 0) {
      // ---- ONE poll point: gather partials (tid<256) || h pairs (256..383) ----
      if (tid < 256) {
        const unsigned long long* base = ywp + b * 2048 + tid;
        unsigned long long v[8];
        for (;;) {
          bool ok = true;
#pragma unroll
          for (int mm = 0; mm < 8; ++mm)
            v[mm] = __hip_atomic_load(base + mm * 256, __ATOMIC_RELAXED, __HIP_MEMORY_SCOPE_AGENT);
#pragma unroll
          for (int mm = 0; mm < 8; ++mm) ok &= ((unsigned)v[mm] == (unsigned)t);
          if (ok) break;
          __builtin_amdgcn_s_sleep(1);
        }
        float y = 0.f, w = 0.f;
#pragma unroll
        for (int mm = 0; mm < 8; ++mm) {
          unsigned pl = (unsigned)(v[mm] >> 32);
          y += lo16(pl);
          w += hi16(pl);
        }
        w_j = w;
        float yn = __shfl_xor(y, 1);
        if (!(tid & 1)) {
          const int p = tid >> 1, sx = (t - 1) & 31;
          ystoreS[(t - 1) * 128 + ((((p >> 2) ^ sx) << 2) | (p & 3))] = pack2(y, yn);
        }
      } else if (tid < 384) {
        const int p = tid - 256;
        unsigned long long v;
        for (;;) {
          v = __hip_atomic_load(&hx[b * 128 + p], __ATOMIC_RELAXED, __HIP_MEMORY_SCOPE_AGENT);
          if ((unsigned)v == (unsigned)t) break;
          __builtin_amdgcn_s_sleep(1);
        }
        unsigned pair = (unsigned)(v >> 32);
        h2[p] = pair;
        histS[(t - 1) * 128 + ((((p >> 2) ^ ((t - 1) & 31)) << 2) | (p & 3))] = pair;
      }
      __syncthreads();
      // ---- S: scores[s] = hist[s] . h_{t-1}, 4 lanes/s ----
      {
        const int s = tid >> 2, part = tid & 3;
        float a = 0.f;
        if (s < t) {
          const int sx = s & 31;
#pragma unroll
          for (int i = 0; i < 8; ++i) {
            const int c = 4 * i + part;
            uint4 hv = *(const uint4*)&histS[s * 128 + ((c ^ sx) << 2)];
            uint4 qv = *(const uint4*)&h2[c << 2];
            a = dot8(hv, qv, a);
          }
        }
        a += __shfl_xor(a, 1);
        a += __shfl_xor(a, 2);
        if (part == 0 && s < t) sc[s] = a;
      }
      __syncthreads();
      // ---- softmax over sc[0..t) ----
      if (tid < 64) {
        float v0 = (tid < t) ? sc[tid] : -3.0e38f;
        float v1 = (tid + 64 < t) ? sc[tid + 64] : -3.0e38f;
        float mx = fmaxf(v0, v1);
#pragma unroll
        for (int off = 32; off >= 1; off >>= 1) mx = fmaxf(mx, __shfl_xor(mx, off));
        float e0 = (tid < t) ? __expf(v0 - mx) : 0.f;
        float e1 = (tid + 64 < t) ? __expf(v1 - mx) : 0.f;
        float sm = e0 + e1;
#pragma unroll
        for (int off = 32; off >= 1; off >>= 1) sm += __shfl_xor(sm, off);
        float inv = __builtin_amdgcn_rcpf(sm);
        sc[tid] = e0 * inv;
        sc[tid + 64] = e1 * inv;
      }
      __syncthreads();
      // ---- Z: z partials over y history ----
      {
        const int sp = tid >> 7, p2 = tid & 127;
        float c0 = 0.f, c1 = 0.f;
        for (int s = sp; s < t; s += 4) {
          float al = sc[s];
          unsigned yv = ystoreS[s * 128 + ((((p2 >> 2) ^ (s & 31)) << 2) | (p2 & 3))];
          c0 += al * lo16(yv);
          c1 += al * hi16(yv);
        }
        zpartF[sp][2 * p2] = c0;
        zpartF[sp][2 * p2 + 1] = c1;
      }
      __syncthreads();
      // ---- H': h'_j = tanh(ba + w + z) ----
      if (tid < 256) {
        float z = zpartF[0][tid] + zpartF[1][tid] + zpartF[2][tid] + zpartF[3][tid];
        float hv = ftanh(ba_j + w_j + z);
        float o = __shfl_xor(hv, 1);
        if (!(tid & 1)) hp2[tid >> 1] = pack2(hv, o);
      }
      __syncthreads();
    }
    // ---- F: gates row r_local, chunks c==qk (mod 4) ----
    {
      float a = 0.f;
#pragma unroll
      for (int i = 0; i < 8; ++i) {
        const int c = 4 * i + qk;
        uint4 hv = *(const uint4*)&hp2[c << 2];
        a = dot8(wh4[i], hv, a);
      }
      a += __shfl_xor(a, 1);
      a += __shfl_xor(a, 2);
      if (qk == 0) gsl[r_local] = a + gih_v;
    }
    __syncthreads();
    // ---- cell (lanes<32): fast transcendentals, publish h slice ----
    if (tid < 32) {
      float ig = fsig(gsl[tid]);
      float fg = fsig(gsl[32 + tid]);
      float gg = ftanh(gsl[64 + tid]);
      float og = fsig(gsl[96 + tid]);
      float cn = fg * c_reg + ig * gg;
      float hn = og * ftanh(cn);
      c_reg = cn;
      out[((size_t)t * 32 + b) * 256 + m * 32 + tid] = hn;
      if (t == len_b - 1) {
        hfin[b * 256 + m * 32 + tid] = hn;
        cfin[b * 256 + m * 32 + tid] = cn;
      }
      float o = __shfl_xor(hn, 1);
      if (!(tid & 1)) {
        unsigned u = pack2(hn, o);
        hsl2[tid >> 1] = u;
        unsigned long long v =
            ((unsigned long long)u << 32) | (unsigned long long)(unsigned)(t + 1);
        __hip_atomic_store(&hx[b * 128 + m * 16 + (tid >> 1)], v, __ATOMIC_RELAXED,
                           __HIP_MEMORY_SCOPE_AGENT);
      }
    }
    __syncthreads();
    // ---- partials: all 512 threads, (j=tid>>1, type=tid&1), dot-32 on own slice ----
    {
      float acc = 0.f;
#pragma unroll
      for (int c = 0; c < 4; ++c) {
        uint4 hv = *(const uint4*)&hsl2[c * 4];
        acc = dot8(wa4[c], hv, acc);
      }
      float other = __shfl_xor(acc, 1);
      if (!(tid & 1)) {
        unsigned long long v = ((unsigned long long)pack2(acc, other) << 32) |
                               (unsigned long long)(unsigned)(t + 1);
        __hip_atomic_store(&ywp[b * 2048 + m * 256 + (tid >> 1)], v, __ATOMIC_RELAXED,
                           __HIP_MEMORY_SCOPE_AGENT);
      }
    }
    // no barrier needed: loop-top gather touches only global tags + disjoint LDS
  }
}

extern "C" void kernel_launch(void* const* d_in, const int* in_sizes, int n_in,
                              void* d_out, int out_size, void* d_ws, size_t ws_size,
                              hipStream_t stream) {
  const float* embs = (const float*)d_in[0];
  const int* lens = (const int*)d_in[1];
  const float* W_ih = (const float*)d_in[2];
  const float* W_hh = (const float*)d_in[3];
  const float* b_ih = (const float*)d_in[4];
  const float* b_hh = (const float*)d_in[5];
  const float* W_a = (const float*)d_in[6];
  const float* b_a = (const float*)d_in[7];

  float* out = (float*)d_out;                       // [T,B,H]
  float* hfin = out + (size_t)T_DIM * B_DIM * 256;  // [B,H]
  float* cfin = hfin + (size_t)B_DIM * 256;         // [B,H]

  char* ws = (char*)d_ws;
  float* gih = (float*)ws;
  float* W_ihT = (float*)(ws + 16777216);
  uint4* Whh_pack = (uint4*)(ws + 17825792);
  uint4* Wa_pack = (uint4*)(ws + 18350080);
  unsigned long long* ywp = (unsigned long long*)(ws + 18612224);
  unsigned long long* hx = (unsigned long long*)(ws + 19136512);

  pack_weights<<<1024, 256, 0, stream>>>(W_ih, W_hh, W_a, W_ihT, Whh_pack, Wa_pack, ywp, hx);
  compute_gih<<<512, 256, 0, stream>>>(embs, W_ihT, b_ih, b_hh, gih);
  alstm_rec<<<256, 512, 0, stream>>>(lens, gih, Whh_pack, Wa_pack, b_a, hx, ywp, out, hfin,
                                     cfin);
}

// Round 7
// 564.042 us; speedup vs baseline: 4.4138x; 1.1051x over previous
//
#include <hip/hip_runtime.h>

// EncoderALSTM: T=128, B=32, H=256, I=256, 4H=1024.
// Round-7: distributed scores, NO h exchange. Block (b,m) owns slice m*32..+32.
//   score_t[s] = sum_m hist_m[s].h_t^m  -> block m computes partial scores for
//   ALL s from its local history slice right after the cell (tiny: 16 fdot2/thr)
//   and publishes them as tagged u64 pairs, together with y/w partials
//   (y_s = Wa_ctx*h_s, w_s = Wa_h*h_s, per-slice partial dots).
// Consumers poll ONE point per step (ps: 64 thr, yw: 256 thr, concurrent),
// reduce 8 partials, softmax, z = sum alpha_s y_s over f32 y-history (LDS,
// no swizzle), h' = tanh(ba+w+z), gates (register W_hh), cell. ZERO fences.
//
// ws layout (bytes):
//   gih      @0         16,777,216  fp32 [t*32+b][1024]
//   W_ihT    @16777216   1,048,576  fp32 (for compute_gih)
//   Whh_pack @17825792     524,288  uint4 [m][512 thr][8]
//   Wa_pack  @18350080     262,144  uint4 [m][256 j][8] (c<4: ctx cols, c>=4: h cols)
//   ywp      @18612224     524,288  u64 [32 b][8 m][256 j] tagged {y,w} partials
//   psx      @19136512     131,072  u64 [32 b][8 m][64]    tagged score-pair partials

#define T_DIM 128
#define B_DIM 32

typedef _Float16 half2_t __attribute__((ext_vector_type(2)));

static __device__ __forceinline__ unsigned pack2(float a, float b) {
  half2_t h;
  h.x = (_Float16)a;
  h.y = (_Float16)b;
  return __builtin_bit_cast(unsigned, h);
}

static __device__ __forceinline__ float dot2f(unsigned w, unsigned v, float acc) {
  half2_t a = __builtin_bit_cast(half2_t, w);
  half2_t b = __builtin_bit_cast(half2_t, v);
#if __has_builtin(__builtin_amdgcn_fdot2)
  return __builtin_amdgcn_fdot2(a, b, acc, false);
#else
  return acc + (float)a.x * (float)b.x + (float)a.y * (float)b.y;
#endif
}

static __device__ __forceinline__ float dot8(uint4 w, uint4 v, float acc) {
  acc = dot2f(w.x, v.x, acc);
  acc = dot2f(w.y, v.y, acc);
  acc = dot2f(w.z, v.z, acc);
  acc = dot2f(w.w, v.w, acc);
  return acc;
}

static __device__ __forceinline__ float lo16(unsigned u) {
  return (float)__builtin_bit_cast(half2_t, u).x;
}
static __device__ __forceinline__ float hi16(unsigned u) {
  return (float)__builtin_bit_cast(half2_t, u).y;
}

static __device__ __forceinline__ float fsig(float x) {
  return __builtin_amdgcn_rcpf(1.f + __expf(-x));
}
static __device__ __forceinline__ float ftanh(float x) {
  float e = __expf(2.f * x);
  return 1.f - 2.f * __builtin_amdgcn_rcpf(e + 1.f);
}

// ---------------- kernel 0: pack weights + zero tag buffers ----------------
__global__ void pack_weights(const float* __restrict__ W_ih, const float* __restrict__ W_hh,
                             const float* __restrict__ W_a, float* __restrict__ W_ihT,
                             uint4* __restrict__ Whh_pack, uint4* __restrict__ Wa_pack,
                             unsigned long long* __restrict__ ywp,
                             unsigned long long* __restrict__ psx) {
  int n = blockIdx.x * 256 + threadIdx.x;  // 0..262143
  {  // W_ihT[k][r] = W_ih[r][k]
    int k = n >> 10, r = n & 1023;
    W_ihT[n] = W_ih[r * 256 + k];
  }
  if (n < 32768) {  // Whh_pack[m][tid][i]: W_hh[r][(4i+qk)*8 ..+8]
    int m = n >> 12, tid = (n >> 3) & 511, i = n & 7;
    int r_local = tid >> 2, qk = tid & 3;
    int q = r_local >> 5, jl = r_local & 31;
    int r = q * 256 + m * 32 + jl;
    const float* src = W_hh + r * 256 + (4 * i + qk) * 8;
    uint4 v;
    v.x = pack2(src[0], src[1]);
    v.y = pack2(src[2], src[3]);
    v.z = pack2(src[4], src[5]);
    v.w = pack2(src[6], src[7]);
    Whh_pack[n] = v;
  }
  if (n < 16384) {  // Wa_pack[m][j][c]: c<4 -> ctx col m*32+c*8; c>=4 -> h col 256+m*32+(c-4)*8
    int m = n >> 11, j = (n >> 3) & 255, c = n & 7;
    int col0 = (c < 4) ? (m * 32 + c * 8) : (256 + m * 32 + (c - 4) * 8);
    const float* src = W_a + j * 512 + col0;
    uint4 v;
    v.x = pack2(src[0], src[1]);
    v.y = pack2(src[2], src[3]);
    v.z = pack2(src[4], src[5]);
    v.w = pack2(src[6], src[7]);
    Wa_pack[n] = v;
  }
  // zero tag buffers (atomic path, matches consumer)
  if (n < 65536)
    __hip_atomic_store(&ywp[n], 0ull, __ATOMIC_RELAXED, __HIP_MEMORY_SCOPE_AGENT);
  else if (n < 81920)
    __hip_atomic_store(&psx[n - 65536], 0ull, __ATOMIC_RELAXED, __HIP_MEMORY_SCOPE_AGENT);
}

// ---------------- kernel 1: gih = embs @ W_ih^T + b_ih + b_hh ----------------
__global__ void compute_gih(const float* __restrict__ embs, const float* __restrict__ W_ihT,
                            const float* __restrict__ b_ih, const float* __restrict__ b_hh,
                            float* __restrict__ gih) {
  __shared__ float embS[8][256];
  const int tid = threadIdx.x;     // 256 threads
  const int tb0 = blockIdx.x * 8;  // 512 blocks x 8 (t,b) pairs
#pragma unroll
  for (int e = 0; e < 8; ++e) embS[e][tid] = embs[(size_t)(tb0 + e) * 256 + tid];
  __syncthreads();
  float acc[8][4];
#pragma unroll
  for (int e = 0; e < 8; ++e)
#pragma unroll
    for (int q = 0; q < 4; ++q) acc[e][q] = 0.f;
  for (int k = 0; k < 256; ++k) {
    float w0 = W_ihT[k * 1024 + tid];
    float w1 = W_ihT[k * 1024 + tid + 256];
    float w2 = W_ihT[k * 1024 + tid + 512];
    float w3 = W_ihT[k * 1024 + tid + 768];
#pragma unroll
    for (int e = 0; e < 8; ++e) {
      float x = embS[e][k];
      acc[e][0] += x * w0;
      acc[e][1] += x * w1;
      acc[e][2] += x * w2;
      acc[e][3] += x * w3;
    }
  }
#pragma unroll
  for (int q = 0; q < 4; ++q) {
    float bias = b_ih[q * 256 + tid] + b_hh[q * 256 + tid];
#pragma unroll
    for (int e = 0; e < 8; ++e)
      gih[(size_t)(tb0 + e) * 1024 + q * 256 + tid] = acc[e][q] + bias;
  }
}

// ---------------- kernel 2: recurrent, distributed scores ----------------
__global__ void __launch_bounds__(512, 1)
alstm_rec(const int* __restrict__ lens, const float* __restrict__ gih,
          const uint4* __restrict__ Whh_pack, const uint4* __restrict__ Wa_pack,
          const float* __restrict__ b_a, unsigned long long* __restrict__ ywp,
          unsigned long long* __restrict__ psx, float* __restrict__ out,
          float* __restrict__ hfin, float* __restrict__ cfin) {
  const int tid = threadIdx.x;  // 512 threads
  const int b = blockIdx.x & 31;
  const int m = blockIdx.x >> 5;

  __shared__ __align__(16) unsigned histSl[128 * 18];  // own h slice history, 9 KB (stride 18)
  __shared__ __align__(16) float ystoreF[128 * 256];   // y history f32, 128 KB
  __shared__ __align__(16) unsigned hp2[128];          // h' pairs
  __shared__ __align__(16) unsigned hsl2[16];          // own h_t slice pairs
  __shared__ float sc[128];                            // scores -> alpha
  __shared__ float zp[4][256];                         // z partials
  __shared__ float gsl[128];

  // ---- register-resident weights ----
  uint4 wh4[8];
  {
    const uint4* p = Whh_pack + ((size_t)m * 512 + tid) * 8;
#pragma unroll
    for (int i = 0; i < 8; ++i) wh4[i] = p[i];
  }
  uint4 way[4], waw[4];  // W_a slice cols for publish row j_pub
  {
    const int j_pub = (tid - 128) & 255;
    const uint4* p = Wa_pack + ((size_t)m * 256 + j_pub) * 8;
#pragma unroll
    for (int i = 0; i < 4; ++i) way[i] = p[i];
#pragma unroll
    for (int i = 0; i < 4; ++i) waw[i] = p[4 + i];
  }
  const float ba_j = (tid < 256) ? b_a[tid] : 0.f;
  const int len_b = lens[b];
  const int r_local = tid >> 2, qk = tid & 3;
  const int gq = r_local >> 5, gjl = r_local & 31;

  if (tid < 128) hp2[tid] = 0u;
  float c_reg = 0.f;  // lanes tid<32
  __syncthreads();

  for (int t = 0; t < T_DIM; ++t) {
    float gih_v = gih[((size_t)t * 32 + b) * 1024 + gq * 256 + m * 32 + gjl];
    float w_j = 0.f;

    if (t > 0) {
      // ---- ONE poll point: yw partials (tid<256) || score partials (256..319) ----
      if (tid < 256) {
        const unsigned long long* base = ywp + b * 2048 + tid;
        unsigned long long v[8];
        for (;;) {
          bool ok = true;
#pragma unroll
          for (int mm = 0; mm < 8; ++mm)
            v[mm] = __hip_atomic_load(base + mm * 256, __ATOMIC_RELAXED, __HIP_MEMORY_SCOPE_AGENT);
#pragma unroll
          for (int mm = 0; mm < 8; ++mm) ok &= ((unsigned)v[mm] == (unsigned)t);
          if (ok) break;
          __builtin_amdgcn_s_sleep(1);
        }
        float y = 0.f, w = 0.f;
#pragma unroll
        for (int mm = 0; mm < 8; ++mm) {
          unsigned pl = (unsigned)(v[mm] >> 32);
          y += lo16(pl);
          w += hi16(pl);
        }
        w_j = w;
        ystoreF[(t - 1) * 256 + tid] = y;
      } else if (tid < 320) {
        const int p = tid - 256;  // score pair index
        const unsigned long long* base = psx + b * 512 + p;
        unsigned long long v[8];
        for (;;) {
          bool ok = true;
#pragma unroll
          for (int mm = 0; mm < 8; ++mm)
            v[mm] = __hip_atomic_load(base + mm * 64, __ATOMIC_RELAXED, __HIP_MEMORY_SCOPE_AGENT);
#pragma unroll
          for (int mm = 0; mm < 8; ++mm) ok &= ((unsigned)v[mm] == (unsigned)t);
          if (ok) break;
          __builtin_amdgcn_s_sleep(1);
        }
        float s0 = 0.f, s1 = 0.f;
#pragma unroll
        for (int mm = 0; mm < 8; ++mm) {
          unsigned pl = (unsigned)(v[mm] >> 32);
          s0 += lo16(pl);
          s1 += hi16(pl);
        }
        sc[2 * p] = s0;
        sc[2 * p + 1] = s1;
      }
      __syncthreads();
      // ---- softmax over sc[0..t) ----
      if (tid < 64) {
        float v0 = (tid < t) ? sc[tid] : -3.0e38f;
        float v1 = (tid + 64 < t) ? sc[tid + 64] : -3.0e38f;
        float mx = fmaxf(v0, v1);
#pragma unroll
        for (int off = 32; off >= 1; off >>= 1) mx = fmaxf(mx, __shfl_xor(mx, off));
        float e0 = (tid < t) ? __expf(v0 - mx) : 0.f;
        float e1 = (tid + 64 < t) ? __expf(v1 - mx) : 0.f;
        float sm = e0 + e1;
#pragma unroll
        for (int off = 32; off >= 1; off >>= 1) sm += __shfl_xor(sm, off);
        float inv = __builtin_amdgcn_rcpf(sm);
        sc[tid] = e0 * inv;
        sc[tid + 64] = e1 * inv;
      }
      __syncthreads();
      // ---- Z: z partials over f32 y-history, no swizzle ----
      {
        const int sp = tid >> 7, p2 = tid & 127;
        float c0 = 0.f, c1 = 0.f;
        const float* yb = ystoreF + 2 * p2;
        for (int s = sp; s < t; s += 4) {
          float al = sc[s];
          float2 yv = *(const float2*)(yb + s * 256);
          c0 += al * yv.x;
          c1 += al * yv.y;
        }
        zp[sp][2 * p2] = c0;
        zp[sp][2 * p2 + 1] = c1;
      }
      __syncthreads();
      // ---- H': h'_j = tanh(ba + w + z) ----
      if (tid < 256) {
        float z = zp[0][tid] + zp[1][tid] + zp[2][tid] + zp[3][tid];
        float hv = ftanh(ba_j + w_j + z);
        float o = __shfl_xor(hv, 1);
        if (!(tid & 1)) hp2[tid >> 1] = pack2(hv, o);
      }
      __syncthreads();
    }
    // ---- F: gates row r_local, chunks c==qk (mod 4) ----
    {
      float a = 0.f;
#pragma unroll
      for (int i = 0; i < 8; ++i) {
        const int c = 4 * i + qk;
        uint4 hv = *(const uint4*)&hp2[c << 2];
        a = dot8(wh4[i], hv, a);
      }
      a += __shfl_xor(a, 1);
      a += __shfl_xor(a, 2);
      if (qk == 0) gsl[r_local] = a + gih_v;
    }
    __syncthreads();
    // ---- cell (lanes<32): update slice, store local copies ----
    if (tid < 32) {
      float ig = fsig(gsl[tid]);
      float fg = fsig(gsl[32 + tid]);
      float gg = ftanh(gsl[64 + tid]);
      float og = fsig(gsl[96 + tid]);
      float cn = fg * c_reg + ig * gg;
      float hn = og * ftanh(cn);
      c_reg = cn;
      out[((size_t)t * 32 + b) * 256 + m * 32 + tid] = hn;
      if (t == len_b - 1) {
        hfin[b * 256 + m * 32 + tid] = hn;
        cfin[b * 256 + m * 32 + tid] = cn;
      }
      float o = __shfl_xor(hn, 1);
      if (!(tid & 1)) {
        unsigned u = pack2(hn, o);
        hsl2[tid >> 1] = u;
        histSl[t * 18 + (tid >> 1)] = u;
      }
    }
    __syncthreads();
    // ---- publish: score partials (tid<128) + y/w partials (128..383) ----
    if (tid < 128) {
      // partial score for s=tid vs query h_t (own slice): 16 fdot2
      float a = 0.f;
#pragma unroll
      for (int k = 0; k < 8; ++k) {
        uint2 hw = *(const uint2*)&histSl[tid * 18 + 2 * k];
        uint2 qv = *(const uint2*)&hsl2[2 * k];
        a = dot2f(hw.x, qv.x, a);
        a = dot2f(hw.y, qv.y, a);
      }
      float o = __shfl_xor(a, 1);
      if (!(tid & 1)) {
        unsigned long long v = ((unsigned long long)pack2(a, o) << 32) |
                               (unsigned long long)(unsigned)(t + 1);
        __hip_atomic_store(&psx[b * 512 + m * 64 + (tid >> 1)], v, __ATOMIC_RELAXED,
                           __HIP_MEMORY_SCOPE_AGENT);
      }
    } else if (tid < 384) {
      const int j = tid - 128;
      float ay = 0.f, aw = 0.f;
#pragma unroll
      for (int c = 0; c < 4; ++c) {
        uint4 hv = *(const uint4*)&hsl2[c * 4];
        ay = dot8(way[c], hv, ay);
        aw = dot8(waw[c], hv, aw);
      }
      unsigned long long v = ((unsigned long long)pack2(ay, aw) << 32) |
                             (unsigned long long)(unsigned)(t + 1);
      __hip_atomic_store(&ywp[b * 2048 + m * 256 + j], v, __ATOMIC_RELAXED,
                         __HIP_MEMORY_SCOPE_AGENT);
    }
    // no barrier at loop wrap: next poll touches only global tags + disjoint LDS
  }
}

extern "C" void kernel_launch(void* const* d_in, const int* in_sizes, int n_in,
                              void* d_out, int out_size, void* d_ws, size_t ws_size,
                              hipStream_t stream) {
  const float* embs = (const float*)d_in[0];
  const int* lens = (const int*)d_in[1];
  const float* W_ih = (const float*)d_in[2];
  const float* W_hh = (const float*)d_in[3];
  const float* b_ih = (const float*)d_in[4];
  const float* b_hh = (const float*)d_in[5];
  const float* W_a = (const float*)d_in[6];
  const float* b_a = (const float*)d_in[7];

  float* out = (float*)d_out;                       // [T,B,H]
  float* hfin = out + (size_t)T_DIM * B_DIM * 256;  // [B,H]
  float* cfin = hfin + (size_t)B_DIM * 256;         // [B,H]

  char* ws = (char*)d_ws;
  float* gih = (float*)ws;
  float* W_ihT = (float*)(ws + 16777216);
  uint4* Whh_pack = (uint4*)(ws + 17825792);
  uint4* Wa_pack = (uint4*)(ws + 18350080);
  unsigned long long* ywp = (unsigned long long*)(ws + 18612224);
  unsigned long long* psx = (unsigned long long*)(ws + 19136512);

  pack_weights<<<1024, 256, 0, stream>>>(W_ih, W_hh, W_a, W_ihT, Whh_pack, Wa_pack, ywp, psx);
  compute_gih<<<512, 256, 0, stream>>>(embs, W_ihT, b_ih, b_hh, gih);
  alstm_rec<<<256, 512, 0, stream>>>(lens, gih, Whh_pack, Wa_pack, b_a, ywp, psx, out, hfin,
                                     cfin);
}